// Round 13
// baseline (372.680 us; speedup 1.0000x reference)
//
#include <hip/hip_runtime.h>

#define L_ 4
#define H_ 8
#define Nn 1024
#define F_ 128
#define E_ 128
#define FF_ 512
#define OUT_ 64
#define B_ 32
#define KTOT (Nn * F_)  // 131072

typedef unsigned short u16;
typedef __bf16 bf16_t;
typedef __attribute__((ext_vector_type(8))) __bf16 bf16x8;
typedef __attribute__((ext_vector_type(4))) float f32x4;

__device__ __forceinline__ u16 f2b(float v) {
    bf16_t h = (bf16_t)v;
    return __builtin_bit_cast(u16, h);
}
__device__ __forceinline__ float b2f(u16 u) {
    unsigned v = (unsigned)u << 16;
    return __builtin_bit_cast(float, v);
}

// ---- async global->LDS, 16B per lane. Dest = wave-uniform base + lane*16B ----
typedef const __attribute__((address_space(1))) void* gvp;
typedef __attribute__((address_space(3))) void* lvp;
__device__ __forceinline__ void gll16(const void* g, void* l) {
    __builtin_amdgcn_global_load_lds((gvp)g, (lvp)l, 16, 0, 0);
}

// Stage R rows x 64 u16 tile, 256 threads (4 waves), swizzled source.
template <int R>
__device__ __forceinline__ void stage(const u16* __restrict__ g, int ldg,
                                      u16* lds, int w, int l) {
    const int r8 = l >> 3, jq = l & 7;
#pragma unroll
    for (int i = 0; i < R / 32; ++i) {
        const int row0 = w * (R / 4) + i * 8;
        const int row = row0 + r8;
        gll16(g + (long)row * ldg + ((jq ^ (row & 7)) << 3), lds + row0 * 64);
    }
}

// Stage [128 rows][64 u16] with 512 threads (8 waves), swizzled source.
__device__ __forceinline__ void stage128x64(const u16* __restrict__ g, int ldg,
                                            u16* lds, int w, int l) {
    const int r8 = l >> 3, jq = l & 7;
#pragma unroll
    for (int i = 0; i < 2; ++i) {
        const int row0 = i * 64 + w * 8;
        const int row = row0 + r8;
        gll16(g + (long)row * ldg + ((jq ^ (row & 7)) << 3), lds + row0 * 64);
    }
}

// ============ bf16 MFMA GEMM (NT): C[m,n] = sum_k A[m,k]*B[n,k] ============
// EPI: 0 fp32 out; 1 bias+relu->bf16; 3 plain bf16 out.
template <int BM, int BN, bool DUAL, int EPI, int BSH, bool GSWAP, bool DBUF>
__global__ __launch_bounds__(256) void k_mfma(
    const u16* __restrict__ A, int lda, long sAz,
    const u16* __restrict__ Bhp, const u16* __restrict__ Blp, int ldb, long sBz,
    const float* __restrict__ bias,
    float* __restrict__ Cf, u16* __restrict__ Cb, int ldc, long sCz, int K)
{
    constexpr int WN = (BN == 64) ? 1 : ((BM == 64) ? 4 : 2);
    constexpr int WM = 4 / WN;
    constexpr int SM = BM / WM, SN = BN / WN;
    constexpr int MF = SM / 16, NF = SN / 16;
    constexpr int BUFE = BM * 64 + (DUAL ? 2 : 1) * BN * 64;
    __shared__ __align__(16) u16 lds[BUFE * (DBUF ? 2 : 1)];
    const int t = threadIdx.x;
    const int w = t >> 6, l = t & 63, lr = l & 15, lg = l >> 4;
    const int wm0 = (w / WN) * SM, wn0 = (w % WN) * SN;
    const int bidm = GSWAP ? blockIdx.z : blockIdx.x;
    const int bidz = GSWAP ? blockIdx.x : blockIdx.z;
    const int m0 = bidm * BM, n0 = blockIdx.y * BN;
    A += BSH ? ((long)(bidz >> 1) * sAz + (long)(bidz & 1) * 128)
             : (long)bidz * sAz;
    Bhp += (long)(bidz >> BSH) * sBz;
    if (DUAL) Blp += (long)bidz * sBz;

    f32x4 acc[MF][NF] = {};

    auto stageAll = [&](u16* base, int k0) {
        stage<BM>(A + (long)m0 * lda + k0, lda, base, w, l);
        stage<BN>(Bhp + (long)n0 * ldb + k0, ldb, base + BM * 64, w, l);
        if (DUAL) stage<BN>(Blp + (long)n0 * ldb + k0, ldb, base + BM * 64 + BN * 64, w, l);
    };
    auto compute = [&](const u16* base) {
        const u16* Al = base;
        const u16* Bh = base + BM * 64;
        const u16* Bl = Bh + BN * 64;
#pragma unroll
        for (int ks = 0; ks < 2; ++ks) {
            bf16x8 af[MF], bh[NF], bl[NF];
            const int kq = ks * 4 + lg;
#pragma unroll
            for (int mf = 0; mf < MF; ++mf) {
                int row = wm0 + mf * 16 + lr;
                af[mf] = *reinterpret_cast<const bf16x8*>(&Al[row * 64 + ((kq ^ (row & 7)) << 3)]);
            }
#pragma unroll
            for (int nf = 0; nf < NF; ++nf) {
                int row = wn0 + nf * 16 + lr;
                int off = row * 64 + ((kq ^ (row & 7)) << 3);
                bh[nf] = *reinterpret_cast<const bf16x8*>(&Bh[off]);
                if (DUAL) bl[nf] = *reinterpret_cast<const bf16x8*>(&Bl[off]);
            }
#pragma unroll
            for (int mf = 0; mf < MF; ++mf)
#pragma unroll
                for (int nf = 0; nf < NF; ++nf) {
                    acc[mf][nf] = __builtin_amdgcn_mfma_f32_16x16x32_bf16(af[mf], bh[nf], acc[mf][nf], 0, 0, 0);
                    if (DUAL)
                        acc[mf][nf] = __builtin_amdgcn_mfma_f32_16x16x32_bf16(af[mf], bl[nf], acc[mf][nf], 0, 0, 0);
                }
        }
    };

    if (DBUF) {
        stageAll(lds, 0);
        __syncthreads();
        int cur = 0;
        for (int k0 = 0; k0 < K; k0 += 64) {
            if (k0 + 64 < K) stageAll(lds + (cur ^ 1) * BUFE, k0 + 64);
            compute(lds + cur * BUFE);
            __syncthreads();
            cur ^= 1;
        }
    } else {
        for (int k0 = 0; k0 < K; k0 += 64) {
            __syncthreads();
            stageAll(lds, k0);
            __syncthreads();
            compute(lds);
        }
    }

    float bv[NF];
    if (EPI == 1) {
#pragma unroll
        for (int nf = 0; nf < NF; ++nf) bv[nf] = bias[n0 + wn0 + nf * 16 + lr];
    }
    if (EPI == 1 || EPI == 3) Cb += (long)bidz * sCz;
    else                      Cf += (long)bidz * sCz;
#pragma unroll
    for (int mf = 0; mf < MF; ++mf)
#pragma unroll
        for (int nf = 0; nf < NF; ++nf)
#pragma unroll
            for (int r = 0; r < 4; ++r) {
                long row = m0 + wm0 + mf * 16 + lg * 4 + r;
                int col = n0 + wn0 + nf * 16 + lr;
                float v = acc[mf][nf][r];
                if (EPI == 1) Cb[row * ldc + col] = f2b(fmaxf(v + bv[nf], 0.f));
                else if (EPI == 3) Cb[row * ldc + col] = f2b(v);
                else Cf[row * ldc + col] = v;
            }
}

// ===== Fused FF1+FF2+residual+LN2 v6: 512 thr, 128-row tiles, grid 256 =====
// W double-buffered, gll prefetch issued a full MFMA phase before its drain
// (true T14): W2(c) before FF1(c), W1(c+1) before FF2(c). 2 barriers/chunk.
// LDS 128 KB: A [0,16384); P [16384,32768); Wbuf0 [32768,49152); Wbuf1 [49152,65536).
template <bool LAST>
__global__ __launch_bounds__(512) void k_ff_ln2(
    const u16* __restrict__ xb,   // [32768][128] bf16 (LN1 out)
    const u16* __restrict__ W1b,  // [512][128] bf16
    const float* __restrict__ b1,
    const u16* __restrict__ W2b,  // [128][512] bf16
    const float* __restrict__ b2,
    float* __restrict__ xc,       // [32768][128] residual in / out
    const float* __restrict__ g, const float* __restrict__ be,
    u16* __restrict__ xh,         // !LAST: [b][f][n] bf16
    float* __restrict__ xsp,      // !LAST: [b][8][128] partials
    u16* __restrict__ xrb)        //  LAST: relu(out) bf16
{
    __shared__ __align__(16) u16 lds[65536];     // 128 KB
    const int t = threadIdx.x;
    const int w = t >> 6, l = t & 63, lr = l & 15, lg = l >> 4;
    const int wr = w >> 2, wc = w & 3;
    const int wn0 = wc * 32;
    const int m0 = blockIdx.x * 128;
    u16* A0 = lds;
    u16* P0 = lds + 16384;
    u16* Wb0 = lds + 32768;
    u16* Wb1 = lds + 49152;

    // prologue: A + W1_0; hoist residual (all loads drain at first barrier)
    stage128x64(xb + (long)m0 * F_,      F_, A0, w, l);
    stage128x64(xb + (long)m0 * F_ + 64, F_, A0 + 8192, w, l);
    stage128x64(W1b,      F_, Wb0, w, l);
    stage128x64(W1b + 64, F_, Wb0 + 8192, w, l);
    float xcr[32];
#pragma unroll
    for (int rr = 0; rr < 16; ++rr) {
        const long xof = (long)(m0 + w * 16 + rr) * F_;
        xcr[rr * 2]     = xc[xof + l];
        xcr[rr * 2 + 1] = xc[xof + l + 64];
    }
    __syncthreads();

    f32x4 acc2[4][2] = {};
    for (int c = 0; c < 4; ++c) {
        // prefetch W2_c -> buf1 (drains at barrier #1, hidden under FF1)
        stage128x64(W2b + c * 128,      FF_, Wb1, w, l);
        stage128x64(W2b + c * 128 + 64, FF_, Wb1 + 8192, w, l);
        // ---- FF1_c: acc1 = A x W1_c(buf0) ----
        f32x4 acc1[4][2] = {};
#pragma unroll
        for (int s = 0; s < 4; ++s) {
            const int kh = s >> 1, kq = (s & 1) * 4 + lg;
            bf16x8 af[4], bfr[2];
#pragma unroll
            for (int mf = 0; mf < 4; ++mf) {
                int row = wr * 64 + mf * 16 + lr;
                af[mf] = *reinterpret_cast<const bf16x8*>(
                    &A0[kh * 8192 + row * 64 + ((kq ^ (row & 7)) << 3)]);
            }
#pragma unroll
            for (int nf = 0; nf < 2; ++nf) {
                int row = wn0 + nf * 16 + lr;
                bfr[nf] = *reinterpret_cast<const bf16x8*>(
                    &Wb0[kh * 8192 + row * 64 + ((kq ^ (row & 7)) << 3)]);
            }
#pragma unroll
            for (int mf = 0; mf < 4; ++mf)
#pragma unroll
                for (int nf = 0; nf < 2; ++nf)
                    acc1[mf][nf] = __builtin_amdgcn_mfma_f32_16x16x32_bf16(af[mf], bfr[nf], acc1[mf][nf], 0, 0, 0);
        }
        // bias + relu -> P (swizzled)
        float b1v[2] = { b1[c * 128 + wn0 + lr], b1[c * 128 + wn0 + 16 + lr] };
#pragma unroll
        for (int mf = 0; mf < 4; ++mf)
#pragma unroll
            for (int nf = 0; nf < 2; ++nf)
#pragma unroll
                for (int r = 0; r < 4; ++r) {
                    int row = wr * 64 + mf * 16 + lg * 4 + r;
                    int sp = (row ^ (row >> 3)) & 7;
                    int cc = wn0 + nf * 16 + lr;
                    int c6 = cc & 63;
                    float v = fmaxf(acc1[mf][nf][r] + b1v[nf], 0.f);
                    P0[(cc >> 6) * 8192 + row * 64 + (((c6 >> 3) ^ sp) << 3) + (c6 & 7)] = f2b(v);
                }
        __syncthreads();   // #1: W2_c drained, P visible, buf0 free
        if (c < 3) {       // prefetch W1_{c+1} -> buf0 (drains at #2, hidden under FF2)
            stage128x64(W1b + (long)(c + 1) * 128 * F_,      F_, Wb0, w, l);
            stage128x64(W1b + (long)(c + 1) * 128 * F_ + 64, F_, Wb0 + 8192, w, l);
        }
        // ---- FF2_c: acc2 += P x W2_c(buf1) ----
#pragma unroll
        for (int s = 0; s < 4; ++s) {
            const int kh = s >> 1, kq = (s & 1) * 4 + lg;
            bf16x8 af[4], bfr[2];
#pragma unroll
            for (int mf = 0; mf < 4; ++mf) {
                int row = wr * 64 + mf * 16 + lr;
                int sp = (row ^ (row >> 3)) & 7;
                af[mf] = *reinterpret_cast<const bf16x8*>(
                    &P0[kh * 8192 + row * 64 + ((kq ^ sp) << 3)]);
            }
#pragma unroll
            for (int nf = 0; nf < 2; ++nf) {
                int row = wn0 + nf * 16 + lr;
                bfr[nf] = *reinterpret_cast<const bf16x8*>(
                    &Wb1[kh * 8192 + row * 64 + ((kq ^ (row & 7)) << 3)]);
            }
#pragma unroll
            for (int mf = 0; mf < 4; ++mf)
#pragma unroll
                for (int nf = 0; nf < 2; ++nf)
                    acc2[mf][nf] = __builtin_amdgcn_mfma_f32_16x16x32_bf16(af[mf], bfr[nf], acc2[mf][nf], 0, 0, 0);
        }
        __syncthreads();   // #2: W1_{c+1} drained, P free, buf1 free
    }
    // epilogue: overlay buf [128][132] f32 + ps [8][128]
    float (*buf)[132] = (float(*)[132])lds;                 // 67584 B
    float (*ps)[128]  = (float(*)[128])((char*)lds + 69632);
    float bv[2] = { b2[wn0 + lr], b2[wn0 + 16 + lr] };
#pragma unroll
    for (int mf = 0; mf < 4; ++mf)
#pragma unroll
        for (int nf = 0; nf < 2; ++nf)
#pragma unroll
            for (int r = 0; r < 4; ++r)
                buf[wr * 64 + mf * 16 + lg * 4 + r][wn0 + nf * 16 + lr] = acc2[mf][nf][r] + bv[nf];
    __syncthreads();
    const float gl0 = g[l], gl1 = g[l + 64], bl0 = be[l], bl1 = be[l + 64];
    float s0 = 0.f, s1 = 0.f;
#pragma unroll
    for (int rr = 0; rr < 16; ++rr) {
        const int row = w * 16 + rr;
        const long xb_ = (long)(m0 + row) * F_;
        float v0 = buf[row][l] + xcr[rr * 2];
        float v1 = buf[row][l + 64] + xcr[rr * 2 + 1];
        float sum = v0 + v1;
#pragma unroll
        for (int o = 32; o; o >>= 1) sum += __shfl_xor(sum, o);
        const float mean = sum * (1.f / 128.f);
        const float d0 = v0 - mean, d1 = v1 - mean;
        float vs = d0 * d0 + d1 * d1;
#pragma unroll
        for (int o = 32; o; o >>= 1) vs += __shfl_xor(vs, o);
        const float rstd = rsqrtf(vs * (1.f / 128.f) + 1e-5f);
        float o0 = d0 * rstd * gl0 + bl0;
        float o1 = d1 * rstd * gl1 + bl1;
        if (LAST) {
            xrb[xb_ + l] = f2b(fmaxf(o0, 0.f));
            xrb[xb_ + l + 64] = f2b(fmaxf(o1, 0.f));
        } else {
            xc[xb_ + l] = o0;       xc[xb_ + l + 64] = o1;
            buf[row][l] = o0;       buf[row][l + 64] = o1;
            s0 += o0;               s1 += o1;
        }
    }
    if (!LAST) {
        ps[w][l] = s0; ps[w][l + 64] = s1;
        __syncthreads();
        const int b = m0 >> 10, nb0 = m0 & 1023, seg = (m0 >> 7) & 7;
        const int n8 = (t & 15) * 8, fb = t >> 4;
#pragma unroll
        for (int i = 0; i < 4; ++i) {
            const int f = fb + 32 * i;
            union { u16 u[8]; float4 v; } Hv;
#pragma unroll
            for (int j = 0; j < 8; ++j) Hv.u[j] = f2b(buf[n8 + j][f]);
            *reinterpret_cast<float4*>(&xh[((long)b * F_ + f) * Nn + nb0 + n8]) = Hv.v;
        }
        if (t < 128) {
            float s = 0.f;
#pragma unroll
            for (int k = 0; k < 8; ++k) s += ps[k][t];
            xsp[((long)b * 8 + seg) * 128 + t] = s;
        }
    }
}

// ============ final projection: out[b,o] = relu(x).Wo^T, k-split MFMA ============
__global__ __launch_bounds__(256) void k_final_mfma(
    const u16* __restrict__ xrb, const u16* __restrict__ Wob,
    float* __restrict__ part)
{
    __shared__ __align__(16) u16 Al[32 * 512];
    const int c = blockIdx.x;
    const long k0 = (long)c * 512;
    const int t = threadIdx.x, w = t >> 6, l = t & 63, lr = l & 15, lg = l >> 4;
#pragma unroll
    for (int i = 0; i < 8; ++i) {
        int ch = i * 256 + t, row = ch >> 6, jq = ch & 63;
        *reinterpret_cast<float4*>(&Al[row * 512 + ((jq ^ (row & 7)) << 3)]) =
            *reinterpret_cast<const float4*>(&xrb[(long)row * KTOT + k0 + (jq << 3)]);
    }
    __syncthreads();
    f32x4 acc[2] = {};
    const u16* Bp = Wob + (long)(w * 16 + lr) * KTOT + k0 + lg * 8;
#pragma unroll
    for (int ks = 0; ks < 16; ++ks) {
        bf16x8 bfr = *reinterpret_cast<const bf16x8*>(Bp + ks * 32);
        const int j8 = ks * 4 + lg;
#pragma unroll
        for (int mf = 0; mf < 2; ++mf) {
            int row = mf * 16 + lr;
            bf16x8 af = *reinterpret_cast<const bf16x8*>(&Al[row * 512 + ((j8 ^ (row & 7)) << 3)]);
            acc[mf] = __builtin_amdgcn_mfma_f32_16x16x32_bf16(af, bfr, acc[mf], 0, 0, 0);
        }
    }
#pragma unroll
    for (int mf = 0; mf < 2; ++mf)
#pragma unroll
        for (int r = 0; r < 4; ++r) {
            int b = mf * 16 + lg * 4 + r, o = w * 16 + lr;
            part[((long)c * B_ + b) * OUT_ + o] = acc[mf][r];
        }
}

__global__ void k_final_reduce(const float* __restrict__ part,
                               const float* __restrict__ bo, float* __restrict__ out)
{
    int i = blockIdx.x * 256 + threadIdx.x;
    int o = i & 63;
    float s = bo[o];
    for (int c = 0; c < 256; ++c) s += part[(long)c * (B_ * OUT_) + i];
    out[i] = s;
}

// ---------------- small kernels ----------------
__global__ __launch_bounds__(256) void k_maskT(const int* __restrict__ adj,
                                               u16* __restrict__ maskTb,
                                               int* __restrict__ degi)
{
    __shared__ u16 tl[64][65];
    const int j0 = blockIdx.x * 64, n0 = blockIdx.y * 64, t = threadIdx.x;
#pragma unroll
    for (int i = 0; i < 16; ++i) {
        int s = i * 256 + t, jl = s >> 6, nl = s & 63;
        tl[jl][nl] = (adj[(long)(j0 + jl) * Nn + n0 + nl] > 0) ? 0x3F80 : 0;
    }
    __syncthreads();
    if (t < 64) {
        int c = 0;
#pragma unroll
        for (int jl = 0; jl < 64; ++jl) c += (tl[jl][t] != 0);
        atomicAdd(&degi[n0 + t], c);
    }
#pragma unroll
    for (int i = 0; i < 16; ++i) {
        int s = i * 256 + t, nl = s >> 6, jl = s & 63;
        maskTb[(long)(n0 + nl) * Nn + j0 + jl] = tl[jl][nl];
    }
}

__global__ __launch_bounds__(256) void k_tpb(const float* __restrict__ in,
                                             u16* __restrict__ out, int R, int C)
{
    __shared__ float tl[64][65];
    const int c0 = blockIdx.x * 64, r0 = blockIdx.y * 64, t = threadIdx.x;
    in  += (long)blockIdx.z * R * C;
    out += (long)blockIdx.z * R * C;
#pragma unroll
    for (int i = 0; i < 16; ++i) {
        int s = i * 256 + t, rl = s >> 6, cl = s & 63;
        tl[rl][cl] = in[(long)(r0 + rl) * C + c0 + cl];
    }
    __syncthreads();
#pragma unroll
    for (int i = 0; i < 16; ++i) {
        int s = i * 256 + t, cl = s >> 6, rl = s & 63;
        out[(long)(c0 + cl) * R + r0 + rl] = f2b(tl[rl][cl]);
    }
}

__global__ void k_cvtW(const float* __restrict__ W1, const float* __restrict__ W2,
                       u16* __restrict__ W1b, u16* __restrict__ W2b)
{
    int i = blockIdx.x * 256 + threadIdx.x;
    W1b[i] = f2b(W1[i]);
    W2b[i] = f2b(W2[i]);
}

__global__ void k_cvtWo(const float* __restrict__ Wo, u16* __restrict__ Wob)
{
    long i = ((long)blockIdx.x * 256 + threadIdx.x) * 8;
    float4 a = *reinterpret_cast<const float4*>(&Wo[i]);
    float4 b = *reinterpret_cast<const float4*>(&Wo[i + 4]);
    union { u16 u[8]; float4 v; } r;
    r.u[0] = f2b(a.x); r.u[1] = f2b(a.y); r.u[2] = f2b(a.z); r.u[3] = f2b(a.w);
    r.u[4] = f2b(b.x); r.u[5] = f2b(b.y); r.u[6] = f2b(b.z); r.u[7] = f2b(b.w);
    *reinterpret_cast<float4*>(&Wob[i]) = r.v;
}

// x[b][n][f] fp32 -> xh[b][f][n] bf16 — prolog only
__global__ __launch_bounds__(256) void k_xpose(const float* __restrict__ x,
                                               u16* __restrict__ xh)
{
    __shared__ float tile[64][132];
    const int b = blockIdx.y, n0 = blockIdx.x * 64, t = threadIdx.x;
#pragma unroll
    for (int i = 0; i < 8; ++i) {
        int s = i * 256 + t, nl = s >> 5, f4 = (s & 31) << 2;
        float4 v = *reinterpret_cast<const float4*>(&x[((long)b * Nn + n0 + nl) * F_ + f4]);
        tile[nl][f4] = v.x; tile[nl][f4 + 1] = v.y;
        tile[nl][f4 + 2] = v.z; tile[nl][f4 + 3] = v.w;
    }
    __syncthreads();
    const int f = t >> 1, nb = (t & 1) << 5;
    const long ob = ((long)b * F_ + f) * Nn + n0 + nb;
    union { u16 u[8]; float4 v; } Hv;
#pragma unroll
    for (int i = 0; i < 32; i += 8) {
#pragma unroll
        for (int j = 0; j < 8; ++j) Hv.u[j] = f2b(tile[nb + i + j][f]);
        *reinterpret_cast<float4*>(&xh[ob + i]) = Hv.v;
    }
}

// layer-0 column partials: xsp[b][seg8][f] = sum over 128 n-rows
__global__ __launch_bounds__(256) void k_xs2(const float* __restrict__ x, float* __restrict__ xsp)
{
    __shared__ float sh[2][128];
    const int seg = blockIdx.x, b = blockIdx.y, t = threadIdx.x;
    const int f = t & 127, h2 = t >> 7;
    const float* p = x + ((long)b * Nn + seg * 128 + h2 * 64) * F_ + f;
    float s = 0.f;
    for (int i = 0; i < 64; ++i) s += p[(long)i * F_];
    sh[h2][f] = s;
    __syncthreads();
    if (t < 128) xsp[((long)b * 8 + seg) * 128 + t] = sh[0][t] + sh[1][t];
}

__global__ void k_hsum(const float* __restrict__ xsp, const float* __restrict__ Wl,
                       const float* __restrict__ bsl, float* __restrict__ hsum)
{
    __shared__ float xs[128];
    const int i = blockIdx.x * 256 + threadIdx.x;
    const int b = i >> 10;
    if (threadIdx.x < 128) {
        const float* xp = xsp + (long)b * 8 * 128 + threadIdx.x;
        float v = 0.f;
#pragma unroll
        for (int sg = 0; sg < 8; ++sg) v += xp[sg * 128];
        xs[threadIdx.x] = v;
    }
    __syncthreads();
    const int e = i & 127, h = (i >> 7) & 7;
    const float* w = Wl + ((long)h * E_ + e) * F_;
    float s = 0.f;
    for (int f = 0; f < F_; ++f) s += xs[f] * w[f];
    hsum[i] = s + (float)Nn * bsl[h * E_ + e];
}

__global__ void k_d12(const float* __restrict__ As, const float* __restrict__ bs,
                      float* __restrict__ d12all)
{
    const int lyr = blockIdx.y;
    const float* Asl = As + (long)lyr * H_ * 2 * E_ * Nn;
    const float* bsl = bs + (long)lyr * H_ * E_;
    int i = blockIdx.x * 256 + threadIdx.x;
    int n = i & 1023, h = (i >> 10) & 7, w = i >> 13;
    const float* a = Asl + ((long)h * 2 * E_ + (long)w * E_) * Nn + n;
    const float* bb = bsl + h * E_;
    float s = 0.f;
    for (int e = 0; e < E_; ++e) s += bb[e] * a[(long)e * Nn];
    d12all[(long)lyr * 2 * H_ * Nn + ((long)w * H_ + h) * Nn + n] = s;
}

__global__ __launch_bounds__(256) void k_score_ln1(
    float* __restrict__ x, const u16* __restrict__ y,
    const float* __restrict__ Ct, const float* __restrict__ d12,
    const int* __restrict__ degi, const float* __restrict__ hsum,
    const float* __restrict__ g, const float* __restrict__ be,
    u16* __restrict__ xb)
{
    const int n = blockIdx.x, t = threadIdx.x;
    __shared__ float c1[H_][128], c2[H_][128];
    __shared__ float sbs[H_];
#pragma unroll
    for (int i = 0; i < 4; ++i) {
        int s = i * 256 + t, h = s >> 7, f = s & 127;
        c1[h][f] = Ct[((long)(2 * h) * Nn + n) * F_ + f];
        c2[h][f] = Ct[((long)(2 * h + 1) * Nn + n) * F_ + f];
    }
    if (t < H_) sbs[t] = d12[(long)t * Nn + n] + (float)degi[n] * d12[(long)(H_ + t) * Nn + n];
    __syncthreads();
    const int w = t >> 6, l = t & 63;
    const float gl0 = g[l], gl1 = g[l + 64], bl0 = be[l], bl1 = be[l + 64];
    for (int bi = 0; bi < 8; ++bi) {
        const int b = w * 8 + bi;
        const long base = ((long)b * Nn + n) * F_;
        float x0 = x[base + l], x1 = x[base + l + 64];
        float y0 = b2f(y[base + l]), y1 = b2f(y[base + l + 64]);
        float a0 = 0.f, a1 = 0.f;
#pragma unroll
        for (int h = 0; h < H_; ++h) {
            float p = x0 * c1[h][l] + x1 * c1[h][l + 64]
                    + y0 * c2[h][l] + y1 * c2[h][l + 64];
#pragma unroll
            for (int o = 32; o; o >>= 1) p += __shfl_xor(p, o);
            float s = p + sbs[h];
            float h0 = hsum[((long)b * H_ + h) * E_ + l];
            float h1 = hsum[((long)b * H_ + h) * E_ + l + 64];
            float p0 = s * h0, p1 = s * h1;
            a0 += (p0 > 0.f ? p0 : 0.01f * p0);
            a1 += (p1 > 0.f ? p1 : 0.01f * p1);
        }
        float v0 = x0 + a0, v1 = x1 + a1;
        float sum = v0 + v1;
#pragma unroll
        for (int o = 32; o; o >>= 1) sum += __shfl_xor(sum, o);
        const float mean = sum * (1.f / 128.f);
        const float d0 = v0 - mean, d1 = v1 - mean;
        float vs = d0 * d0 + d1 * d1;
#pragma unroll
        for (int o = 32; o; o >>= 1) vs += __shfl_xor(vs, o);
        const float rstd = rsqrtf(vs * (1.f / 128.f) + 1e-5f);
        float o0 = d0 * rstd * gl0 + bl0;
        float o1 = d1 * rstd * gl1 + bl1;
        x[base + l] = o0;        x[base + l + 64] = o1;
        xb[base + l] = f2b(o0);  xb[base + l + 64] = f2b(o1);
    }
}

extern "C" void kernel_launch(void* const* d_in, const int* in_sizes, int n_in,
                              void* d_out, int out_size, void* d_ws, size_t ws_size,
                              hipStream_t stream)
{
    const float* x_in = (const float*)d_in[0];
    const int*   adj  = (const int*)d_in[1];
    const float* Ws   = (const float*)d_in[2];
    const float* bs   = (const float*)d_in[3];
    const float* As   = (const float*)d_in[4];
    const float* W1   = (const float*)d_in[5];
    const float* b1   = (const float*)d_in[6];
    const float* W2   = (const float*)d_in[7];
    const float* b2   = (const float*)d_in[8];
    const float* g1   = (const float*)d_in[9];
    const float* be1  = (const float*)d_in[10];
    const float* g2   = (const float*)d_in[11];
    const float* be2  = (const float*)d_in[12];
    const float* Wo   = (const float*)d_in[13];
    const float* bo   = (const float*)d_in[14];
    float* out = (float*)d_out;

    char* wsb = (char*)d_ws;
    u16*   maskTb = (u16*)wsb;                        //   0: 2 MB
    float* xc     = (float*)(wsb + (2L << 20));       //   2: 16 MB
    u16*   yb     = (u16*)(wsb + (18L << 20));        //  18: 8 MB bf16
    float* CtAll  = (float*)(wsb + (66L << 20));      //  66: 32 MB [L][16][Nn][F]
    u16*   xb     = (u16*)(wsb + (98L << 20));        //  98: 8 MB
    u16*   xrb    = (u16*)(wsb + (106L << 20));       // 106: 8 MB
    u16*   Wob    = (u16*)(wsb + (114L << 20));       // 114: 16 MB
    float* part   = (float*)(wsb + (130L << 20));     // 130: 2 MB
    u16*   xTh    = (u16*)(wsb + (132L << 20));       // 132: 8 MB
    u16*   AsTb   = (u16*)(wsb + (148L << 20));       // 148: 16 MB [LH][n][e2]
    u16*   WsTb   = (u16*)(wsb + (164L << 20));       // 164: 2 MB [LH][f][e]
    char*  S      = wsb + (166L << 20);
    int*   degi   = (int*)S;                          // 4 KB
    float* xsp    = (float*)(S + (4L << 10));         // 128 KB [b][8][128]
    float* hsum   = (float*)(S + (132L << 10));       // 128 KB
    float* d12all = (float*)(S + (260L << 10));       // 256 KB
    u16*   W1b    = (u16*)(S + (516L << 10));         // 512 KB
    u16*   W2b    = (u16*)(S + (1028L << 10));        // 512 KB

    hipMemsetAsync(degi, 0, Nn * sizeof(int), stream);
    hipMemcpyAsync(xc, x_in, sizeof(float) * (long)B_ * Nn * F_,
                   hipMemcpyDeviceToDevice, stream);
    k_maskT<<<dim3(16, 16), 256, 0, stream>>>(adj, maskTb, degi);
    k_cvtW<<<(L_ * FF_ * F_) / 256, 256, 0, stream>>>(W1, W2, W1b, W2b);
    k_cvtWo<<<(OUT_ * KTOT) / (256 * 8), 256, 0, stream>>>(Wo, Wob);
    k_tpb<<<dim3(16, 4, L_ * H_), 256, 0, stream>>>(As, AsTb, 2 * E_, Nn);
    k_tpb<<<dim3(2, 2, L_ * H_), 256, 0, stream>>>(Ws, WsTb, E_, F_);
    k_xpose<<<dim3(16, B_), 256, 0, stream>>>(x_in, xTh);
    k_xs2<<<dim3(8, B_), 256, 0, stream>>>(x_in, xsp);
    k_d12<<<dim3((2 * H_ * Nn) / 256, L_), 256, 0, stream>>>(As, bs, d12all);
    // CtAll[l][2h+p][n][f] = sum_e AsT[l,h][n][p*128+e] * WsT[l,h][f][e]
    k_mfma<64, 128, false, 0, 1, false, false><<<dim3(16, 1, 64), 256, 0, stream>>>(
        AsTb, 2 * E_, (long)Nn * 2 * E_, WsTb, nullptr, E_, (long)F_ * E_,
        nullptr, CtAll, nullptr, F_, (long)Nn * F_, E_);

    for (int l = 0; l < L_; ++l) {
        const float* Wl  = Ws + (long)l * H_ * E_ * F_;
        const float* bsl = bs + (long)l * H_ * E_;

        // y[b][n][f] = sum_j mask[j][n] x[b][j][f]  (single bf16 plane, bf16 out)
        k_mfma<128, 64, false, 3, 0, true, true><<<dim3(32, 2, 8), 256, 0, stream>>>(
            maskTb, Nn, 0L, xTh, nullptr, Nn, (long)F_ * Nn,
            nullptr, nullptr, yb, F_, (long)Nn * F_, Nn);

        k_hsum<<<(B_ * H_ * E_) / 256, 256, 0, stream>>>(xsp, Wl, bsl, hsum);
        k_score_ln1<<<Nn, 256, 0, stream>>>(
            xc, yb, CtAll + (long)l * 16 * Nn * F_, d12all + (long)l * 2 * H_ * Nn,
            degi, hsum, g1 + l * F_, be1 + l * F_, xb);
        // fused FF1+FF2+LN2 v6 (512 thr, 128-row tiles, W-dbuf prefetch)
        if (l < L_ - 1)
            k_ff_ln2<false><<<256, 512, 0, stream>>>(
                xb, W1b + (long)l * FF_ * F_, b1 + l * FF_,
                W2b + (long)l * F_ * FF_, b2 + l * F_, xc,
                g2 + l * F_, be2 + l * F_, xTh, xsp, nullptr);
        else
            k_ff_ln2<true><<<256, 512, 0, stream>>>(
                xb, W1b + (long)l * FF_ * F_, b1 + l * FF_,
                W2b + (long)l * F_ * FF_, b2 + l * F_, xc,
                g2 + l * F_, be2 + l * F_, nullptr, nullptr, xrb);
    }

    k_final_mfma<<<256, 256, 0, stream>>>(xrb, Wob, part);
    k_final_reduce<<<(B_ * OUT_) / 256, 256, 0, stream>>>(part, bo, out);
}

// Round 14
// 363.985 us; speedup vs baseline: 1.0239x; 1.0239x over previous
//
#include <hip/hip_runtime.h>

#define L_ 4
#define H_ 8
#define Nn 1024
#define F_ 128
#define E_ 128
#define FF_ 512
#define OUT_ 64
#define B_ 32
#define KTOT (Nn * F_)  // 131072

typedef unsigned short u16;
typedef __bf16 bf16_t;
typedef __attribute__((ext_vector_type(8))) __bf16 bf16x8;
typedef __attribute__((ext_vector_type(4))) float f32x4;

__device__ __forceinline__ u16 f2b(float v) {
    bf16_t h = (bf16_t)v;
    return __builtin_bit_cast(u16, h);
}
__device__ __forceinline__ float b2f(u16 u) {
    unsigned v = (unsigned)u << 16;
    return __builtin_bit_cast(float, v);
}

// ---- async global->LDS, 16B per lane ----
typedef const __attribute__((address_space(1))) void* gvp;
typedef __attribute__((address_space(3))) void* lvp;
__device__ __forceinline__ void gll16(const void* g, void* l) {
    __builtin_amdgcn_global_load_lds((gvp)g, (lvp)l, 16, 0, 0);
}

// Stage R rows x 64 u16 tile, 256 threads (4 waves), swizzled source.
template <int R>
__device__ __forceinline__ void stage(const u16* __restrict__ g, int ldg,
                                      u16* lds, int w, int l) {
    const int r8 = l >> 3, jq = l & 7;
#pragma unroll
    for (int i = 0; i < R / 32; ++i) {
        const int row0 = w * (R / 4) + i * 8;
        const int row = row0 + r8;
        gll16(g + (long)row * ldg + ((jq ^ (row & 7)) << 3), lds + row0 * 64);
    }
}

// Stage [128 rows][64 u16] with 512 threads (8 waves), swizzled source.
__device__ __forceinline__ void stage128x64(const u16* __restrict__ g, int ldg,
                                            u16* lds, int w, int l) {
    const int r8 = l >> 3, jq = l & 7;
#pragma unroll
    for (int i = 0; i < 2; ++i) {
        const int row0 = i * 64 + w * 8;
        const int row = row0 + r8;
        gll16(g + (long)row * ldg + ((jq ^ (row & 7)) << 3), lds + row0 * 64);
    }
}

// ============ bf16 MFMA GEMM (NT): C[m,n] = sum_k A[m,k]*B[n,k] ============
// EPI: 0 fp32 out; 1 bias+relu->bf16; 3 plain bf16 out.
template <int BM, int BN, bool DUAL, int EPI, int BSH, bool GSWAP, bool DBUF>
__global__ __launch_bounds__(256) void k_mfma(
    const u16* __restrict__ A, int lda, long sAz,
    const u16* __restrict__ Bhp, const u16* __restrict__ Blp, int ldb, long sBz,
    const float* __restrict__ bias,
    float* __restrict__ Cf, u16* __restrict__ Cb, int ldc, long sCz, int K)
{
    constexpr int WN = (BN == 64) ? 1 : ((BM == 64) ? 4 : 2);
    constexpr int WM = 4 / WN;
    constexpr int SM = BM / WM, SN = BN / WN;
    constexpr int MF = SM / 16, NF = SN / 16;
    constexpr int BUFE = BM * 64 + (DUAL ? 2 : 1) * BN * 64;
    __shared__ __align__(16) u16 lds[BUFE * (DBUF ? 2 : 1)];
    const int t = threadIdx.x;
    const int w = t >> 6, l = t & 63, lr = l & 15, lg = l >> 4;
    const int wm0 = (w / WN) * SM, wn0 = (w % WN) * SN;
    const int bidm = GSWAP ? blockIdx.z : blockIdx.x;
    const int bidz = GSWAP ? blockIdx.x : blockIdx.z;
    const int m0 = bidm * BM, n0 = blockIdx.y * BN;
    A += BSH ? ((long)(bidz >> 1) * sAz + (long)(bidz & 1) * 128)
             : (long)bidz * sAz;
    Bhp += (long)(bidz >> BSH) * sBz;
    if (DUAL) Blp += (long)bidz * sBz;

    f32x4 acc[MF][NF] = {};

    auto stageAll = [&](u16* base, int k0) {
        stage<BM>(A + (long)m0 * lda + k0, lda, base, w, l);
        stage<BN>(Bhp + (long)n0 * ldb + k0, ldb, base + BM * 64, w, l);
        if (DUAL) stage<BN>(Blp + (long)n0 * ldb + k0, ldb, base + BM * 64 + BN * 64, w, l);
    };
    auto compute = [&](const u16* base) {
        const u16* Al = base;
        const u16* Bh = base + BM * 64;
        const u16* Bl = Bh + BN * 64;
#pragma unroll
        for (int ks = 0; ks < 2; ++ks) {
            bf16x8 af[MF], bh[NF], bl[NF];
            const int kq = ks * 4 + lg;
#pragma unroll
            for (int mf = 0; mf < MF; ++mf) {
                int row = wm0 + mf * 16 + lr;
                af[mf] = *reinterpret_cast<const bf16x8*>(&Al[row * 64 + ((kq ^ (row & 7)) << 3)]);
            }
#pragma unroll
            for (int nf = 0; nf < NF; ++nf) {
                int row = wn0 + nf * 16 + lr;
                int off = row * 64 + ((kq ^ (row & 7)) << 3);
                bh[nf] = *reinterpret_cast<const bf16x8*>(&Bh[off]);
                if (DUAL) bl[nf] = *reinterpret_cast<const bf16x8*>(&Bl[off]);
            }
#pragma unroll
            for (int mf = 0; mf < MF; ++mf)
#pragma unroll
                for (int nf = 0; nf < NF; ++nf) {
                    acc[mf][nf] = __builtin_amdgcn_mfma_f32_16x16x32_bf16(af[mf], bh[nf], acc[mf][nf], 0, 0, 0);
                    if (DUAL)
                        acc[mf][nf] = __builtin_amdgcn_mfma_f32_16x16x32_bf16(af[mf], bl[nf], acc[mf][nf], 0, 0, 0);
                }
        }
    };

    if (DBUF) {
        stageAll(lds, 0);
        __syncthreads();
        int cur = 0;
        for (int k0 = 0; k0 < K; k0 += 64) {
            if (k0 + 64 < K) stageAll(lds + (cur ^ 1) * BUFE, k0 + 64);
            compute(lds + cur * BUFE);
            __syncthreads();
            cur ^= 1;
        }
    } else {
        for (int k0 = 0; k0 < K; k0 += 64) {
            __syncthreads();
            stageAll(lds, k0);
            __syncthreads();
            compute(lds);
        }
    }

    float bv[NF];
    if (EPI == 1) {
#pragma unroll
        for (int nf = 0; nf < NF; ++nf) bv[nf] = bias[n0 + wn0 + nf * 16 + lr];
    }
    if (EPI == 1 || EPI == 3) Cb += (long)bidz * sCz;
    else                      Cf += (long)bidz * sCz;
#pragma unroll
    for (int mf = 0; mf < MF; ++mf)
#pragma unroll
        for (int nf = 0; nf < NF; ++nf)
#pragma unroll
            for (int r = 0; r < 4; ++r) {
                long row = m0 + wm0 + mf * 16 + lg * 4 + r;
                int col = n0 + wn0 + nf * 16 + lr;
                float v = acc[mf][nf][r];
                if (EPI == 1) Cb[row * ldc + col] = f2b(fmaxf(v + bv[nf], 0.f));
                else if (EPI == 3) Cb[row * ldc + col] = f2b(v);
                else Cf[row * ldc + col] = v;
            }
}

// ===== Fused FF1+FF2+residual+LN2 v7: all-bf16 activations. 512 thr, 128-row =====
// Residual = LN1 out = the A tile already in LDS (read back via same XOR).
// LDS bytes: A [0,32768); P [32768,65536); Wb0 [65536,98304); Wb1 [98304,131072).
// Epilogue buf overlays P+W at byte 32768 (A preserved for residual reads).
template <bool LAST>
__global__ __launch_bounds__(512) void k_ff_ln2(
    const u16* __restrict__ xb,   // [32768][128] bf16 (LN1 out)  = A + residual
    const u16* __restrict__ W1b,  // [512][128] bf16
    const float* __restrict__ b1,
    const u16* __restrict__ W2b,  // [128][512] bf16
    const float* __restrict__ b2,
    const float* __restrict__ g, const float* __restrict__ be,
    u16* __restrict__ xbn,        // !LAST: LN2 out bf16 row-major (next layer input)
    u16* __restrict__ xh,         // !LAST: [b][f][n] bf16 transposed
    float* __restrict__ xsp,      // !LAST: [b][8][128] column partials
    u16* __restrict__ xrb)        //  LAST: relu(LN2 out) bf16
{
    __shared__ __align__(16) u16 lds[65536];     // 128 KB
    const int t = threadIdx.x;
    const int w = t >> 6, l = t & 63, lr = l & 15, lg = l >> 4;
    const int wr = w >> 2, wc = w & 3;
    const int wn0 = wc * 32;
    const int m0 = blockIdx.x * 128;
    u16* A0 = lds;
    u16* P0 = lds + 16384;
    u16* Wb0 = lds + 32768;
    u16* Wb1 = lds + 49152;

    // prologue: A + W1_0
    stage128x64(xb + (long)m0 * F_,      F_, A0, w, l);
    stage128x64(xb + (long)m0 * F_ + 64, F_, A0 + 8192, w, l);
    stage128x64(W1b,      F_, Wb0, w, l);
    stage128x64(W1b + 64, F_, Wb0 + 8192, w, l);
    __syncthreads();

    f32x4 acc2[4][2] = {};
    for (int c = 0; c < 4; ++c) {
        // prefetch W2_c -> buf1 (drains at barrier #1)
        stage128x64(W2b + c * 128,      FF_, Wb1, w, l);
        stage128x64(W2b + c * 128 + 64, FF_, Wb1 + 8192, w, l);
        // ---- FF1_c: acc1 = A x W1_c(buf0) ----
        f32x4 acc1[4][2] = {};
#pragma unroll
        for (int s = 0; s < 4; ++s) {
            const int kh = s >> 1, kq = (s & 1) * 4 + lg;
            bf16x8 af[4], bfr[2];
#pragma unroll
            for (int mf = 0; mf < 4; ++mf) {
                int row = wr * 64 + mf * 16 + lr;
                af[mf] = *reinterpret_cast<const bf16x8*>(
                    &A0[kh * 8192 + row * 64 + ((kq ^ (row & 7)) << 3)]);
            }
#pragma unroll
            for (int nf = 0; nf < 2; ++nf) {
                int row = wn0 + nf * 16 + lr;
                bfr[nf] = *reinterpret_cast<const bf16x8*>(
                    &Wb0[kh * 8192 + row * 64 + ((kq ^ (row & 7)) << 3)]);
            }
#pragma unroll
            for (int mf = 0; mf < 4; ++mf)
#pragma unroll
                for (int nf = 0; nf < 2; ++nf)
                    acc1[mf][nf] = __builtin_amdgcn_mfma_f32_16x16x32_bf16(af[mf], bfr[nf], acc1[mf][nf], 0, 0, 0);
        }
        // bias + relu -> P (swizzled)
        float b1v[2] = { b1[c * 128 + wn0 + lr], b1[c * 128 + wn0 + 16 + lr] };
#pragma unroll
        for (int mf = 0; mf < 4; ++mf)
#pragma unroll
            for (int nf = 0; nf < 2; ++nf)
#pragma unroll
                for (int r = 0; r < 4; ++r) {
                    int row = wr * 64 + mf * 16 + lg * 4 + r;
                    int sp = (row ^ (row >> 3)) & 7;
                    int cc = wn0 + nf * 16 + lr;
                    int c6 = cc & 63;
                    float v = fmaxf(acc1[mf][nf][r] + b1v[nf], 0.f);
                    P0[(cc >> 6) * 8192 + row * 64 + (((c6 >> 3) ^ sp) << 3) + (c6 & 7)] = f2b(v);
                }
        __syncthreads();   // #1: W2_c drained, P visible, buf0 free
        if (c < 3) {       // prefetch W1_{c+1} -> buf0
            stage128x64(W1b + (long)(c + 1) * 128 * F_,      F_, Wb0, w, l);
            stage128x64(W1b + (long)(c + 1) * 128 * F_ + 64, F_, Wb0 + 8192, w, l);
        }
        // ---- FF2_c: acc2 += P x W2_c(buf1) ----
#pragma unroll
        for (int s = 0; s < 4; ++s) {
            const int kh = s >> 1, kq = (s & 1) * 4 + lg;
            bf16x8 af[4], bfr[2];
#pragma unroll
            for (int mf = 0; mf < 4; ++mf) {
                int row = wr * 64 + mf * 16 + lr;
                int sp = (row ^ (row >> 3)) & 7;
                af[mf] = *reinterpret_cast<const bf16x8*>(
                    &P0[kh * 8192 + row * 64 + ((kq ^ sp) << 3)]);
            }
#pragma unroll
            for (int nf = 0; nf < 2; ++nf) {
                int row = wn0 + nf * 16 + lr;
                bfr[nf] = *reinterpret_cast<const bf16x8*>(
                    &Wb1[kh * 8192 + row * 64 + ((kq ^ (row & 7)) << 3)]);
            }
#pragma unroll
            for (int mf = 0; mf < 4; ++mf)
#pragma unroll
                for (int nf = 0; nf < 2; ++nf)
                    acc2[mf][nf] = __builtin_amdgcn_mfma_f32_16x16x32_bf16(af[mf], bfr[nf], acc2[mf][nf], 0, 0, 0);
        }
        __syncthreads();   // #2: W1_{c+1} drained, P free, buf1 free
    }
    // epilogue: buf overlays P+W (A preserved); ps after buf
    float (*buf)[132] = (float(*)[132])((char*)lds + 32768);   // 67584 B
    float (*ps)[128]  = (float(*)[128])((char*)lds + 100352);  // 4 KB
    float bv[2] = { b2[wn0 + lr], b2[wn0 + 16 + lr] };
#pragma unroll
    for (int mf = 0; mf < 4; ++mf)
#pragma unroll
        for (int nf = 0; nf < 2; ++nf)
#pragma unroll
            for (int r = 0; r < 4; ++r)
                buf[wr * 64 + mf * 16 + lg * 4 + r][wn0 + nf * 16 + lr] = acc2[mf][nf][r] + bv[nf];
    __syncthreads();
    const float gl0 = g[l], gl1 = g[l + 64], bl0 = be[l], bl1 = be[l + 64];
    float s0 = 0.f, s1 = 0.f;
#pragma unroll
    for (int rr = 0; rr < 16; ++rr) {
        const int row = w * 16 + rr;
        const long xb_ = (long)(m0 + row) * F_;
        // residual from the A tile still in LDS (swizzled bf16)
        const int sw = (row & 7);
        float r0 = b2f(A0[row * 64 + ((((l >> 3) ^ sw)) << 3) + (l & 7)]);
        float r1 = b2f(A0[8192 + row * 64 + ((((l >> 3) ^ sw)) << 3) + (l & 7)]);
        float v0 = buf[row][l] + r0;
        float v1 = buf[row][l + 64] + r1;
        float sum = v0 + v1;
#pragma unroll
        for (int o = 32; o; o >>= 1) sum += __shfl_xor(sum, o);
        const float mean = sum * (1.f / 128.f);
        const float d0 = v0 - mean, d1 = v1 - mean;
        float vs = d0 * d0 + d1 * d1;
#pragma unroll
        for (int o = 32; o; o >>= 1) vs += __shfl_xor(vs, o);
        const float rstd = rsqrtf(vs * (1.f / 128.f) + 1e-5f);
        float o0 = d0 * rstd * gl0 + bl0;
        float o1 = d1 * rstd * gl1 + bl1;
        if (LAST) {
            xrb[xb_ + l] = f2b(fmaxf(o0, 0.f));
            xrb[xb_ + l + 64] = f2b(fmaxf(o1, 0.f));
        } else {
            xbn[xb_ + l] = f2b(o0);
            xbn[xb_ + l + 64] = f2b(o1);
            buf[row][l] = o0;       buf[row][l + 64] = o1;
            s0 += o0;               s1 += o1;
        }
    }
    if (!LAST) {
        ps[w][l] = s0; ps[w][l + 64] = s1;
        __syncthreads();
        const int b = m0 >> 10, nb0 = m0 & 1023, seg = (m0 >> 7) & 7;
        const int n8 = (t & 15) * 8, fb = t >> 4;
#pragma unroll
        for (int i = 0; i < 4; ++i) {
            const int f = fb + 32 * i;
            union { u16 u[8]; float4 v; } Hv;
#pragma unroll
            for (int j = 0; j < 8; ++j) Hv.u[j] = f2b(buf[n8 + j][f]);
            *reinterpret_cast<float4*>(&xh[((long)b * F_ + f) * Nn + nb0 + n8]) = Hv.v;
        }
        if (t < 128) {
            float s = 0.f;
#pragma unroll
            for (int k = 0; k < 8; ++k) s += ps[k][t];
            xsp[((long)b * 8 + seg) * 128 + t] = s;
        }
    }
}

// ============ final projection: out[b,o] = relu(x).Wo^T, k-split MFMA ============
__global__ __launch_bounds__(256) void k_final_mfma(
    const u16* __restrict__ xrb, const u16* __restrict__ Wob,
    float* __restrict__ part)
{
    __shared__ __align__(16) u16 Al[32 * 512];
    const int c = blockIdx.x;
    const long k0 = (long)c * 512;
    const int t = threadIdx.x, w = t >> 6, l = t & 63, lr = l & 15, lg = l >> 4;
#pragma unroll
    for (int i = 0; i < 8; ++i) {
        int ch = i * 256 + t, row = ch >> 6, jq = ch & 63;
        *reinterpret_cast<float4*>(&Al[row * 512 + ((jq ^ (row & 7)) << 3)]) =
            *reinterpret_cast<const float4*>(&xrb[(long)row * KTOT + k0 + (jq << 3)]);
    }
    __syncthreads();
    f32x4 acc[2] = {};
    const u16* Bp = Wob + (long)(w * 16 + lr) * KTOT + k0 + lg * 8;
#pragma unroll
    for (int ks = 0; ks < 16; ++ks) {
        bf16x8 bfr = *reinterpret_cast<const bf16x8*>(Bp + ks * 32);
        const int j8 = ks * 4 + lg;
#pragma unroll
        for (int mf = 0; mf < 2; ++mf) {
            int row = mf * 16 + lr;
            bf16x8 af = *reinterpret_cast<const bf16x8*>(&Al[row * 512 + ((j8 ^ (row & 7)) << 3)]);
            acc[mf] = __builtin_amdgcn_mfma_f32_16x16x32_bf16(af, bfr, acc[mf], 0, 0, 0);
        }
    }
#pragma unroll
    for (int mf = 0; mf < 2; ++mf)
#pragma unroll
        for (int r = 0; r < 4; ++r) {
            int b = mf * 16 + lg * 4 + r, o = w * 16 + lr;
            part[((long)c * B_ + b) * OUT_ + o] = acc[mf][r];
        }
}

__global__ void k_final_reduce(const float* __restrict__ part,
                               const float* __restrict__ bo, float* __restrict__ out)
{
    int i = blockIdx.x * 256 + threadIdx.x;
    int o = i & 63;
    float s = bo[o];
    for (int c = 0; c < 256; ++c) s += part[(long)c * (B_ * OUT_) + i];
    out[i] = s;
}

// ---------------- small kernels ----------------
__global__ __launch_bounds__(256) void k_maskT(const int* __restrict__ adj,
                                               u16* __restrict__ maskTb,
                                               int* __restrict__ degi)
{
    __shared__ u16 tl[64][65];
    const int j0 = blockIdx.x * 64, n0 = blockIdx.y * 64, t = threadIdx.x;
#pragma unroll
    for (int i = 0; i < 16; ++i) {
        int s = i * 256 + t, jl = s >> 6, nl = s & 63;
        tl[jl][nl] = (adj[(long)(j0 + jl) * Nn + n0 + nl] > 0) ? 0x3F80 : 0;
    }
    __syncthreads();
    if (t < 64) {
        int c = 0;
#pragma unroll
        for (int jl = 0; jl < 64; ++jl) c += (tl[jl][t] != 0);
        atomicAdd(&degi[n0 + t], c);
    }
#pragma unroll
    for (int i = 0; i < 16; ++i) {
        int s = i * 256 + t, nl = s >> 6, jl = s & 63;
        maskTb[(long)(n0 + nl) * Nn + j0 + jl] = tl[jl][nl];
    }
}

__global__ __launch_bounds__(256) void k_tpb(const float* __restrict__ in,
                                             u16* __restrict__ out, int R, int C)
{
    __shared__ float tl[64][65];
    const int c0 = blockIdx.x * 64, r0 = blockIdx.y * 64, t = threadIdx.x;
    in  += (long)blockIdx.z * R * C;
    out += (long)blockIdx.z * R * C;
#pragma unroll
    for (int i = 0; i < 16; ++i) {
        int s = i * 256 + t, rl = s >> 6, cl = s & 63;
        tl[rl][cl] = in[(long)(r0 + rl) * C + c0 + cl];
    }
    __syncthreads();
#pragma unroll
    for (int i = 0; i < 16; ++i) {
        int s = i * 256 + t, cl = s >> 6, rl = s & 63;
        out[(long)(c0 + cl) * R + r0 + rl] = f2b(tl[rl][cl]);
    }
}

__global__ void k_cvtW(const float* __restrict__ W1, const float* __restrict__ W2,
                       u16* __restrict__ W1b, u16* __restrict__ W2b)
{
    int i = blockIdx.x * 256 + threadIdx.x;
    W1b[i] = f2b(W1[i]);
    W2b[i] = f2b(W2[i]);
}

__global__ void k_cvtWo(const float* __restrict__ Wo, u16* __restrict__ Wob)
{
    long i = ((long)blockIdx.x * 256 + threadIdx.x) * 8;
    float4 a = *reinterpret_cast<const float4*>(&Wo[i]);
    float4 b = *reinterpret_cast<const float4*>(&Wo[i + 4]);
    union { u16 u[8]; float4 v; } r;
    r.u[0] = f2b(a.x); r.u[1] = f2b(a.y); r.u[2] = f2b(a.z); r.u[3] = f2b(a.w);
    r.u[4] = f2b(b.x); r.u[5] = f2b(b.y); r.u[6] = f2b(b.z); r.u[7] = f2b(b.w);
    *reinterpret_cast<float4*>(&Wob[i]) = r.v;
}

// fp32 -> bf16 row-major convert (x_in -> xA), 8 elems/thread
__global__ void k_cvtX(const float* __restrict__ x, u16* __restrict__ xo)
{
    long i = ((long)blockIdx.x * 256 + threadIdx.x) * 8;
    float4 a = *reinterpret_cast<const float4*>(&x[i]);
    float4 b = *reinterpret_cast<const float4*>(&x[i + 4]);
    union { u16 u[8]; float4 v; } r;
    r.u[0] = f2b(a.x); r.u[1] = f2b(a.y); r.u[2] = f2b(a.z); r.u[3] = f2b(a.w);
    r.u[4] = f2b(b.x); r.u[5] = f2b(b.y); r.u[6] = f2b(b.z); r.u[7] = f2b(b.w);
    *reinterpret_cast<float4*>(&xo[i]) = r.v;
}

// x[b][n][f] fp32 -> xh[b][f][n] bf16 — prolog only
__global__ __launch_bounds__(256) void k_xpose(const float* __restrict__ x,
                                               u16* __restrict__ xh)
{
    __shared__ float tile[64][132];
    const int b = blockIdx.y, n0 = blockIdx.x * 64, t = threadIdx.x;
#pragma unroll
    for (int i = 0; i < 8; ++i) {
        int s = i * 256 + t, nl = s >> 5, f4 = (s & 31) << 2;
        float4 v = *reinterpret_cast<const float4*>(&x[((long)b * Nn + n0 + nl) * F_ + f4]);
        tile[nl][f4] = v.x; tile[nl][f4 + 1] = v.y;
        tile[nl][f4 + 2] = v.z; tile[nl][f4 + 3] = v.w;
    }
    __syncthreads();
    const int f = t >> 1, nb = (t & 1) << 5;
    const long ob = ((long)b * F_ + f) * Nn + n0 + nb;
    union { u16 u[8]; float4 v; } Hv;
#pragma unroll
    for (int i = 0; i < 32; i += 8) {
#pragma unroll
        for (int j = 0; j < 8; ++j) Hv.u[j] = f2b(tile[nb + i + j][f]);
        *reinterpret_cast<float4*>(&xh[ob + i]) = Hv.v;
    }
}

// layer-0 column partials: xsp[b][seg8][f] = sum over 128 n-rows
__global__ __launch_bounds__(256) void k_xs2(const float* __restrict__ x, float* __restrict__ xsp)
{
    __shared__ float sh[2][128];
    const int seg = blockIdx.x, b = blockIdx.y, t = threadIdx.x;
    const int f = t & 127, h2 = t >> 7;
    const float* p = x + ((long)b * Nn + seg * 128 + h2 * 64) * F_ + f;
    float s = 0.f;
    for (int i = 0; i < 64; ++i) s += p[(long)i * F_];
    sh[h2][f] = s;
    __syncthreads();
    if (t < 128) xsp[((long)b * 8 + seg) * 128 + t] = sh[0][t] + sh[1][t];
}

__global__ void k_hsum(const float* __restrict__ xsp, const float* __restrict__ Wl,
                       const float* __restrict__ bsl, float* __restrict__ hsum)
{
    __shared__ float xs[128];
    const int i = blockIdx.x * 256 + threadIdx.x;
    const int b = i >> 10;
    if (threadIdx.x < 128) {
        const float* xp = xsp + (long)b * 8 * 128 + threadIdx.x;
        float v = 0.f;
#pragma unroll
        for (int sg = 0; sg < 8; ++sg) v += xp[sg * 128];
        xs[threadIdx.x] = v;
    }
    __syncthreads();
    const int e = i & 127, h = (i >> 7) & 7;
    const float* w = Wl + ((long)h * E_ + e) * F_;
    float s = 0.f;
    for (int f = 0; f < F_; ++f) s += xs[f] * w[f];
    hsum[i] = s + (float)Nn * bsl[h * E_ + e];
}

__global__ void k_d12(const float* __restrict__ As, const float* __restrict__ bs,
                      float* __restrict__ d12all)
{
    const int lyr = blockIdx.y;
    const float* Asl = As + (long)lyr * H_ * 2 * E_ * Nn;
    const float* bsl = bs + (long)lyr * H_ * E_;
    int i = blockIdx.x * 256 + threadIdx.x;
    int n = i & 1023, h = (i >> 10) & 7, w = i >> 13;
    const float* a = Asl + ((long)h * 2 * E_ + (long)w * E_) * Nn + n;
    const float* bb = bsl + h * E_;
    float s = 0.f;
    for (int e = 0; e < E_; ++e) s += bb[e] * a[(long)e * Nn];
    d12all[(long)lyr * 2 * H_ * Nn + ((long)w * H_ + h) * Nn + n] = s;
}

// fused score + attention + residual + LN1 (all-bf16 activations)
__global__ __launch_bounds__(256) void k_score_ln1(
    const u16* __restrict__ xA, const u16* __restrict__ y,
    const u16* __restrict__ Ctb, const float* __restrict__ d12,
    const int* __restrict__ degi, const float* __restrict__ hsum,
    const float* __restrict__ g, const float* __restrict__ be,
    u16* __restrict__ xb)
{
    const int n = blockIdx.x, t = threadIdx.x;
    __shared__ float c1[H_][128], c2[H_][128];
    __shared__ float sbs[H_];
#pragma unroll
    for (int i = 0; i < 4; ++i) {
        int s = i * 256 + t, h = s >> 7, f = s & 127;
        c1[h][f] = b2f(Ctb[((long)(2 * h) * Nn + n) * F_ + f]);
        c2[h][f] = b2f(Ctb[((long)(2 * h + 1) * Nn + n) * F_ + f]);
    }
    if (t < H_) sbs[t] = d12[(long)t * Nn + n] + (float)degi[n] * d12[(long)(H_ + t) * Nn + n];
    __syncthreads();
    const int w = t >> 6, l = t & 63;
    const float gl0 = g[l], gl1 = g[l + 64], bl0 = be[l], bl1 = be[l + 64];
    for (int bi = 0; bi < 8; ++bi) {
        const int b = w * 8 + bi;
        const long base = ((long)b * Nn + n) * F_;
        float x0 = b2f(xA[base + l]), x1 = b2f(xA[base + l + 64]);
        float y0 = b2f(y[base + l]),  y1 = b2f(y[base + l + 64]);
        float a0 = 0.f, a1 = 0.f;
#pragma unroll
        for (int h = 0; h < H_; ++h) {
            float p = x0 * c1[h][l] + x1 * c1[h][l + 64]
                    + y0 * c2[h][l] + y1 * c2[h][l + 64];
#pragma unroll
            for (int o = 32; o; o >>= 1) p += __shfl_xor(p, o);
            float s = p + sbs[h];
            float h0 = hsum[((long)b * H_ + h) * E_ + l];
            float h1 = hsum[((long)b * H_ + h) * E_ + l + 64];
            float p0 = s * h0, p1 = s * h1;
            a0 += (p0 > 0.f ? p0 : 0.01f * p0);
            a1 += (p1 > 0.f ? p1 : 0.01f * p1);
        }
        float v0 = x0 + a0, v1 = x1 + a1;
        float sum = v0 + v1;
#pragma unroll
        for (int o = 32; o; o >>= 1) sum += __shfl_xor(sum, o);
        const float mean = sum * (1.f / 128.f);
        const float d0 = v0 - mean, d1 = v1 - mean;
        float vs = d0 * d0 + d1 * d1;
#pragma unroll
        for (int o = 32; o; o >>= 1) vs += __shfl_xor(vs, o);
        const float rstd = rsqrtf(vs * (1.f / 128.f) + 1e-5f);
        xb[base + l]      = f2b(d0 * rstd * gl0 + bl0);
        xb[base + l + 64] = f2b(d1 * rstd * gl1 + bl1);
    }
}

extern "C" void kernel_launch(void* const* d_in, const int* in_sizes, int n_in,
                              void* d_out, int out_size, void* d_ws, size_t ws_size,
                              hipStream_t stream)
{
    const float* x_in = (const float*)d_in[0];
    const int*   adj  = (const int*)d_in[1];
    const float* Ws   = (const float*)d_in[2];
    const float* bs   = (const float*)d_in[3];
    const float* As   = (const float*)d_in[4];
    const float* W1   = (const float*)d_in[5];
    const float* b1   = (const float*)d_in[6];
    const float* W2   = (const float*)d_in[7];
    const float* b2   = (const float*)d_in[8];
    const float* g1   = (const float*)d_in[9];
    const float* be1  = (const float*)d_in[10];
    const float* g2   = (const float*)d_in[11];
    const float* be2  = (const float*)d_in[12];
    const float* Wo   = (const float*)d_in[13];
    const float* bo   = (const float*)d_in[14];
    float* out = (float*)d_out;

    char* wsb = (char*)d_ws;
    u16*   maskTb = (u16*)wsb;                        //   0: 2 MB
    u16*   xA     = (u16*)(wsb + (2L << 20));         //   2: 8 MB (layer input bf16)
    u16*   yb     = (u16*)(wsb + (10L << 20));        //  10: 8 MB
    u16*   CtAllb = (u16*)(wsb + (18L << 20));        //  18: 16 MB [L][16][Nn][F] bf16
    u16*   xB     = (u16*)(wsb + (34L << 20));        //  34: 8 MB (LN1 out bf16)
    u16*   xrb    = (u16*)(wsb + (42L << 20));        //  42: 8 MB
    u16*   Wob    = (u16*)(wsb + (50L << 20));        //  50: 16 MB
    float* part   = (float*)(wsb + (66L << 20));      //  66: 2 MB
    u16*   xTh    = (u16*)(wsb + (68L << 20));        //  68: 8 MB
    u16*   AsTb   = (u16*)(wsb + (76L << 20));        //  76: 16 MB [LH][n][e2]
    u16*   WsTb   = (u16*)(wsb + (92L << 20));        //  92: 2 MB [LH][f][e]
    char*  S      = wsb + (94L << 20);
    int*   degi   = (int*)S;                          // 4 KB
    float* xsp    = (float*)(S + (4L << 10));         // 128 KB [b][8][128]
    float* hsum   = (float*)(S + (132L << 10));       // 128 KB
    float* d12all = (float*)(S + (260L << 10));       // 256 KB
    u16*   W1b    = (u16*)(S + (516L << 10));         // 512 KB
    u16*   W2b    = (u16*)(S + (1028L << 10));        // 512 KB

    hipMemsetAsync(degi, 0, Nn * sizeof(int), stream);
    k_maskT<<<dim3(16, 16), 256, 0, stream>>>(adj, maskTb, degi);
    k_cvtW<<<(L_ * FF_ * F_) / 256, 256, 0, stream>>>(W1, W2, W1b, W2b);
    k_cvtWo<<<(OUT_ * KTOT) / (256 * 8), 256, 0, stream>>>(Wo, Wob);
    k_cvtX<<<(B_ * Nn * F_) / (256 * 8), 256, 0, stream>>>(x_in, xA);
    k_tpb<<<dim3(16, 4, L_ * H_), 256, 0, stream>>>(As, AsTb, 2 * E_, Nn);
    k_tpb<<<dim3(2, 2, L_ * H_), 256, 0, stream>>>(Ws, WsTb, E_, F_);
    k_xpose<<<dim3(16, B_), 256, 0, stream>>>(x_in, xTh);
    k_xs2<<<dim3(8, B_), 256, 0, stream>>>(x_in, xsp);
    k_d12<<<dim3((2 * H_ * Nn) / 256, L_), 256, 0, stream>>>(As, bs, d12all);
    // CtAllb[l][2h+p][n][f] = sum_e AsT[l,h][n][p*128+e] * WsT[l,h][f][e] (bf16 out)
    k_mfma<64, 128, false, 3, 1, false, false><<<dim3(16, 1, 64), 256, 0, stream>>>(
        AsTb, 2 * E_, (long)Nn * 2 * E_, WsTb, nullptr, E_, (long)F_ * E_,
        nullptr, nullptr, CtAllb, F_, (long)Nn * F_, E_);

    for (int l = 0; l < L_; ++l) {
        const float* Wl  = Ws + (long)l * H_ * E_ * F_;
        const float* bsl = bs + (long)l * H_ * E_;

        // y[b][n][f] = sum_j mask[j][n] x[b][j][f]  (bf16 in/out)
        k_mfma<128, 64, false, 3, 0, true, true><<<dim3(32, 2, 8), 256, 0, stream>>>(
            maskTb, Nn, 0L, xTh, nullptr, Nn, (long)F_ * Nn,
            nullptr, nullptr, yb, F_, (long)Nn * F_, Nn);

        k_hsum<<<(B_ * H_ * E_) / 256, 256, 0, stream>>>(xsp, Wl, bsl, hsum);
        k_score_ln1<<<Nn, 256, 0, stream>>>(
            xA, yb, CtAllb + (long)l * 16 * Nn * F_, d12all + (long)l * 2 * H_ * Nn,
            degi, hsum, g1 + l * F_, be1 + l * F_, xB);
        // fused FF1+FF2+LN2 v7 (all-bf16; residual from LDS A tile)
        if (l < L_ - 1)
            k_ff_ln2<false><<<256, 512, 0, stream>>>(
                xB, W1b + (long)l * FF_ * F_, b1 + l * FF_,
                W2b + (long)l * F_ * FF_, b2 + l * F_,
                g2 + l * F_, be2 + l * F_, xA, xTh, xsp, nullptr);
        else
            k_ff_ln2<true><<<256, 512, 0, stream>>>(
                xB, W1b + (long)l * FF_ * F_, b1 + l * FF_,
                W2b + (long)l * F_ * FF_, b2 + l * F_,
                g2 + l * F_, be2 + l * F_, nullptr, nullptr, nullptr, xrb);
    }

    k_final_mfma<<<256, 256, 0, stream>>>(xrb, Wob, part);
    k_final_reduce<<<(B_ * OUT_) / 256, 256, 0, stream>>>(part, bo, out);
}

// Round 15
// 363.323 us; speedup vs baseline: 1.0258x; 1.0018x over previous
//
#include <hip/hip_runtime.h>

#define L_ 4
#define H_ 8
#define Nn 1024
#define F_ 128
#define E_ 128
#define FF_ 512
#define OUT_ 64
#define B_ 32
#define KTOT (Nn * F_)  // 131072

typedef unsigned short u16;
typedef __bf16 bf16_t;
typedef __attribute__((ext_vector_type(8))) __bf16 bf16x8;
typedef __attribute__((ext_vector_type(4))) float f32x4;

__device__ __forceinline__ u16 f2b(float v) {
    bf16_t h = (bf16_t)v;
    return __builtin_bit_cast(u16, h);
}
__device__ __forceinline__ float b2f(u16 u) {
    unsigned v = (unsigned)u << 16;
    return __builtin_bit_cast(float, v);
}

// ---- async global->LDS, 16B per lane ----
typedef const __attribute__((address_space(1))) void* gvp;
typedef __attribute__((address_space(3))) void* lvp;
__device__ __forceinline__ void gll16(const void* g, void* l) {
    __builtin_amdgcn_global_load_lds((gvp)g, (lvp)l, 16, 0, 0);
}

// Stage R rows x 64 u16 tile, 256 threads (4 waves), swizzled source.
template <int R>
__device__ __forceinline__ void stage(const u16* __restrict__ g, int ldg,
                                      u16* lds, int w, int l) {
    const int r8 = l >> 3, jq = l & 7;
#pragma unroll
    for (int i = 0; i < R / 32; ++i) {
        const int row0 = w * (R / 4) + i * 8;
        const int row = row0 + r8;
        gll16(g + (long)row * ldg + ((jq ^ (row & 7)) << 3), lds + row0 * 64);
    }
}

// Stage [128 rows][64 u16] with 512 threads (8 waves), swizzled source.
__device__ __forceinline__ void stage128x64(const u16* __restrict__ g, int ldg,
                                            u16* lds, int w, int l) {
    const int r8 = l >> 3, jq = l & 7;
#pragma unroll
    for (int i = 0; i < 2; ++i) {
        const int row0 = i * 64 + w * 8;
        const int row = row0 + r8;
        gll16(g + (long)row * ldg + ((jq ^ (row & 7)) << 3), lds + row0 * 64);
    }
}

// ============ bf16 MFMA GEMM (NT): C[m,n] = sum_k A[m,k]*B[n,k] ============
// EPI: 0 fp32 out; 1 bias+relu->bf16; 3 plain bf16 out.
template <int BM, int BN, bool DUAL, int EPI, int BSH, bool GSWAP, bool DBUF>
__global__ __launch_bounds__(256) void k_mfma(
    const u16* __restrict__ A, int lda, long sAz,
    const u16* __restrict__ Bhp, const u16* __restrict__ Blp, int ldb, long sBz,
    const float* __restrict__ bias,
    float* __restrict__ Cf, u16* __restrict__ Cb, int ldc, long sCz, int K)
{
    constexpr int WN = (BN == 64) ? 1 : ((BM == 64) ? 4 : 2);
    constexpr int WM = 4 / WN;
    constexpr int SM = BM / WM, SN = BN / WN;
    constexpr int MF = SM / 16, NF = SN / 16;
    constexpr int BUFE = BM * 64 + (DUAL ? 2 : 1) * BN * 64;
    __shared__ __align__(16) u16 lds[BUFE * (DBUF ? 2 : 1)];
    const int t = threadIdx.x;
    const int w = t >> 6, l = t & 63, lr = l & 15, lg = l >> 4;
    const int wm0 = (w / WN) * SM, wn0 = (w % WN) * SN;
    const int bidm = GSWAP ? blockIdx.z : blockIdx.x;
    const int bidz = GSWAP ? blockIdx.x : blockIdx.z;
    const int m0 = bidm * BM, n0 = blockIdx.y * BN;
    A += BSH ? ((long)(bidz >> 1) * sAz + (long)(bidz & 1) * 128)
             : (long)bidz * sAz;
    Bhp += (long)(bidz >> BSH) * sBz;
    if (DUAL) Blp += (long)bidz * sBz;

    f32x4 acc[MF][NF] = {};

    auto stageAll = [&](u16* base, int k0) {
        stage<BM>(A + (long)m0 * lda + k0, lda, base, w, l);
        stage<BN>(Bhp + (long)n0 * ldb + k0, ldb, base + BM * 64, w, l);
        if (DUAL) stage<BN>(Blp + (long)n0 * ldb + k0, ldb, base + BM * 64 + BN * 64, w, l);
    };
    auto compute = [&](const u16* base) {
        const u16* Al = base;
        const u16* Bh = base + BM * 64;
        const u16* Bl = Bh + BN * 64;
#pragma unroll
        for (int ks = 0; ks < 2; ++ks) {
            bf16x8 af[MF], bh[NF], bl[NF];
            const int kq = ks * 4 + lg;
#pragma unroll
            for (int mf = 0; mf < MF; ++mf) {
                int row = wm0 + mf * 16 + lr;
                af[mf] = *reinterpret_cast<const bf16x8*>(&Al[row * 64 + ((kq ^ (row & 7)) << 3)]);
            }
#pragma unroll
            for (int nf = 0; nf < NF; ++nf) {
                int row = wn0 + nf * 16 + lr;
                int off = row * 64 + ((kq ^ (row & 7)) << 3);
                bh[nf] = *reinterpret_cast<const bf16x8*>(&Bh[off]);
                if (DUAL) bl[nf] = *reinterpret_cast<const bf16x8*>(&Bl[off]);
            }
#pragma unroll
            for (int mf = 0; mf < MF; ++mf)
#pragma unroll
                for (int nf = 0; nf < NF; ++nf) {
                    acc[mf][nf] = __builtin_amdgcn_mfma_f32_16x16x32_bf16(af[mf], bh[nf], acc[mf][nf], 0, 0, 0);
                    if (DUAL)
                        acc[mf][nf] = __builtin_amdgcn_mfma_f32_16x16x32_bf16(af[mf], bl[nf], acc[mf][nf], 0, 0, 0);
                }
        }
    };

    if (DBUF) {
        stageAll(lds, 0);
        __syncthreads();
        int cur = 0;
        for (int k0 = 0; k0 < K; k0 += 64) {
            if (k0 + 64 < K) stageAll(lds + (cur ^ 1) * BUFE, k0 + 64);
            compute(lds + cur * BUFE);
            __syncthreads();
            cur ^= 1;
        }
    } else {
        for (int k0 = 0; k0 < K; k0 += 64) {
            __syncthreads();
            stageAll(lds, k0);
            __syncthreads();
            compute(lds);
        }
    }

    float bv[NF];
    if (EPI == 1) {
#pragma unroll
        for (int nf = 0; nf < NF; ++nf) bv[nf] = bias[n0 + wn0 + nf * 16 + lr];
    }
    if (EPI == 1 || EPI == 3) Cb += (long)bidz * sCz;
    else                      Cf += (long)bidz * sCz;
#pragma unroll
    for (int mf = 0; mf < MF; ++mf)
#pragma unroll
        for (int nf = 0; nf < NF; ++nf)
#pragma unroll
            for (int r = 0; r < 4; ++r) {
                long row = m0 + wm0 + mf * 16 + lg * 4 + r;
                int col = n0 + wn0 + nf * 16 + lr;
                float v = acc[mf][nf][r];
                if (EPI == 1) Cb[row * ldc + col] = f2b(fmaxf(v + bv[nf], 0.f));
                else if (EPI == 3) Cb[row * ldc + col] = f2b(v);
                else Cf[row * ldc + col] = v;
            }
}

// ===== Fused FF1+FF2+residual+LN2 v7 + T5 setprio around MFMA clusters =====
template <bool LAST>
__global__ __launch_bounds__(512) void k_ff_ln2(
    const u16* __restrict__ xb,   // [32768][128] bf16 (LN1 out) = A + residual
    const u16* __restrict__ W1b,
    const float* __restrict__ b1,
    const u16* __restrict__ W2b,
    const float* __restrict__ b2,
    const float* __restrict__ g, const float* __restrict__ be,
    u16* __restrict__ xbn,        // !LAST: LN2 out bf16 row-major
    u16* __restrict__ xh,         // !LAST: [b][f][n] bf16 transposed
    float* __restrict__ xsp,      // !LAST: [b][8][128] column partials
    u16* __restrict__ xrb)        //  LAST: relu(LN2 out) bf16
{
    __shared__ __align__(16) u16 lds[65536];     // 128 KB
    const int t = threadIdx.x;
    const int w = t >> 6, l = t & 63, lr = l & 15, lg = l >> 4;
    const int wr = w >> 2, wc = w & 3;
    const int wn0 = wc * 32;
    const int m0 = blockIdx.x * 128;
    u16* A0 = lds;
    u16* P0 = lds + 16384;
    u16* Wb0 = lds + 32768;
    u16* Wb1 = lds + 49152;

    stage128x64(xb + (long)m0 * F_,      F_, A0, w, l);
    stage128x64(xb + (long)m0 * F_ + 64, F_, A0 + 8192, w, l);
    stage128x64(W1b,      F_, Wb0, w, l);
    stage128x64(W1b + 64, F_, Wb0 + 8192, w, l);
    __syncthreads();

    f32x4 acc2[4][2] = {};
    for (int c = 0; c < 4; ++c) {
        stage128x64(W2b + c * 128,      FF_, Wb1, w, l);
        stage128x64(W2b + c * 128 + 64, FF_, Wb1 + 8192, w, l);
        // ---- FF1_c ----
        f32x4 acc1[4][2] = {};
        __builtin_amdgcn_s_setprio(1);
#pragma unroll
        for (int s = 0; s < 4; ++s) {
            const int kh = s >> 1, kq = (s & 1) * 4 + lg;
            bf16x8 af[4], bfr[2];
#pragma unroll
            for (int mf = 0; mf < 4; ++mf) {
                int row = wr * 64 + mf * 16 + lr;
                af[mf] = *reinterpret_cast<const bf16x8*>(
                    &A0[kh * 8192 + row * 64 + ((kq ^ (row & 7)) << 3)]);
            }
#pragma unroll
            for (int nf = 0; nf < 2; ++nf) {
                int row = wn0 + nf * 16 + lr;
                bfr[nf] = *reinterpret_cast<const bf16x8*>(
                    &Wb0[kh * 8192 + row * 64 + ((kq ^ (row & 7)) << 3)]);
            }
#pragma unroll
            for (int mf = 0; mf < 4; ++mf)
#pragma unroll
                for (int nf = 0; nf < 2; ++nf)
                    acc1[mf][nf] = __builtin_amdgcn_mfma_f32_16x16x32_bf16(af[mf], bfr[nf], acc1[mf][nf], 0, 0, 0);
        }
        __builtin_amdgcn_s_setprio(0);
        // bias + relu -> P (swizzled)
        float b1v[2] = { b1[c * 128 + wn0 + lr], b1[c * 128 + wn0 + 16 + lr] };
#pragma unroll
        for (int mf = 0; mf < 4; ++mf)
#pragma unroll
            for (int nf = 0; nf < 2; ++nf)
#pragma unroll
                for (int r = 0; r < 4; ++r) {
                    int row = wr * 64 + mf * 16 + lg * 4 + r;
                    int sp = (row ^ (row >> 3)) & 7;
                    int cc = wn0 + nf * 16 + lr;
                    int c6 = cc & 63;
                    float v = fmaxf(acc1[mf][nf][r] + b1v[nf], 0.f);
                    P0[(cc >> 6) * 8192 + row * 64 + (((c6 >> 3) ^ sp) << 3) + (c6 & 7)] = f2b(v);
                }
        __syncthreads();   // #1: W2_c drained, P visible, buf0 free
        if (c < 3) {
            stage128x64(W1b + (long)(c + 1) * 128 * F_,      F_, Wb0, w, l);
            stage128x64(W1b + (long)(c + 1) * 128 * F_ + 64, F_, Wb0 + 8192, w, l);
        }
        // ---- FF2_c ----
        __builtin_amdgcn_s_setprio(1);
#pragma unroll
        for (int s = 0; s < 4; ++s) {
            const int kh = s >> 1, kq = (s & 1) * 4 + lg;
            bf16x8 af[4], bfr[2];
#pragma unroll
            for (int mf = 0; mf < 4; ++mf) {
                int row = wr * 64 + mf * 16 + lr;
                int sp = (row ^ (row >> 3)) & 7;
                af[mf] = *reinterpret_cast<const bf16x8*>(
                    &P0[kh * 8192 + row * 64 + ((kq ^ sp) << 3)]);
            }
#pragma unroll
            for (int nf = 0; nf < 2; ++nf) {
                int row = wn0 + nf * 16 + lr;
                bfr[nf] = *reinterpret_cast<const bf16x8*>(
                    &Wb1[kh * 8192 + row * 64 + ((kq ^ (row & 7)) << 3)]);
            }
#pragma unroll
            for (int mf = 0; mf < 4; ++mf)
#pragma unroll
                for (int nf = 0; nf < 2; ++nf)
                    acc2[mf][nf] = __builtin_amdgcn_mfma_f32_16x16x32_bf16(af[mf], bfr[nf], acc2[mf][nf], 0, 0, 0);
        }
        __builtin_amdgcn_s_setprio(0);
        __syncthreads();   // #2: W1_{c+1} drained, P free, buf1 free
    }
    // epilogue: buf overlays P+W (A preserved for residual reads)
    float (*buf)[132] = (float(*)[132])((char*)lds + 32768);
    float (*ps)[128]  = (float(*)[128])((char*)lds + 100352);
    float bv[2] = { b2[wn0 + lr], b2[wn0 + 16 + lr] };
#pragma unroll
    for (int mf = 0; mf < 4; ++mf)
#pragma unroll
        for (int nf = 0; nf < 2; ++nf)
#pragma unroll
            for (int r = 0; r < 4; ++r)
                buf[wr * 64 + mf * 16 + lg * 4 + r][wn0 + nf * 16 + lr] = acc2[mf][nf][r] + bv[nf];
    __syncthreads();
    const float gl0 = g[l], gl1 = g[l + 64], bl0 = be[l], bl1 = be[l + 64];
    float s0 = 0.f, s1 = 0.f;
#pragma unroll
    for (int rr = 0; rr < 16; ++rr) {
        const int row = w * 16 + rr;
        const long xb_ = (long)(m0 + row) * F_;
        const int sw = (row & 7);
        float r0 = b2f(A0[row * 64 + ((((l >> 3) ^ sw)) << 3) + (l & 7)]);
        float r1 = b2f(A0[8192 + row * 64 + ((((l >> 3) ^ sw)) << 3) + (l & 7)]);
        float v0 = buf[row][l] + r0;
        float v1 = buf[row][l + 64] + r1;
        float sum = v0 + v1;
#pragma unroll
        for (int o = 32; o; o >>= 1) sum += __shfl_xor(sum, o);
        const float mean = sum * (1.f / 128.f);
        const float d0 = v0 - mean, d1 = v1 - mean;
        float vs = d0 * d0 + d1 * d1;
#pragma unroll
        for (int o = 32; o; o >>= 1) vs += __shfl_xor(vs, o);
        const float rstd = rsqrtf(vs * (1.f / 128.f) + 1e-5f);
        float o0 = d0 * rstd * gl0 + bl0;
        float o1 = d1 * rstd * gl1 + bl1;
        if (LAST) {
            xrb[xb_ + l] = f2b(fmaxf(o0, 0.f));
            xrb[xb_ + l + 64] = f2b(fmaxf(o1, 0.f));
        } else {
            xbn[xb_ + l] = f2b(o0);
            xbn[xb_ + l + 64] = f2b(o1);
            buf[row][l] = o0;       buf[row][l + 64] = o1;
            s0 += o0;               s1 += o1;
        }
    }
    if (!LAST) {
        ps[w][l] = s0; ps[w][l + 64] = s1;
        __syncthreads();
        const int b = m0 >> 10, nb0 = m0 & 1023, seg = (m0 >> 7) & 7;
        const int n8 = (t & 15) * 8, fb = t >> 4;
#pragma unroll
        for (int i = 0; i < 4; ++i) {
            const int f = fb + 32 * i;
            union { u16 u[8]; float4 v; } Hv;
#pragma unroll
            for (int j = 0; j < 8; ++j) Hv.u[j] = f2b(buf[n8 + j][f]);
            *reinterpret_cast<float4*>(&xh[((long)b * F_ + f) * Nn + nb0 + n8]) = Hv.v;
        }
        if (t < 128) {
            float s = 0.f;
#pragma unroll
            for (int k = 0; k < 8; ++k) s += ps[k][t];
            xsp[((long)b * 8 + seg) * 128 + t] = s;
        }
    }
}

// ============ final projection: out[b,o] = relu(x).Wo^T, k-split MFMA ============
__global__ __launch_bounds__(256) void k_final_mfma(
    const u16* __restrict__ xrb, const u16* __restrict__ Wob,
    float* __restrict__ part)
{
    __shared__ __align__(16) u16 Al[32 * 512];
    const int c = blockIdx.x;
    const long k0 = (long)c * 512;
    const int t = threadIdx.x, w = t >> 6, l = t & 63, lr = l & 15, lg = l >> 4;
#pragma unroll
    for (int i = 0; i < 8; ++i) {
        int ch = i * 256 + t, row = ch >> 6, jq = ch & 63;
        *reinterpret_cast<float4*>(&Al[row * 512 + ((jq ^ (row & 7)) << 3)]) =
            *reinterpret_cast<const float4*>(&xrb[(long)row * KTOT + k0 + (jq << 3)]);
    }
    __syncthreads();
    f32x4 acc[2] = {};
    const u16* Bp = Wob + (long)(w * 16 + lr) * KTOT + k0 + lg * 8;
#pragma unroll
    for (int ks = 0; ks < 16; ++ks) {
        bf16x8 bfr = *reinterpret_cast<const bf16x8*>(Bp + ks * 32);
        const int j8 = ks * 4 + lg;
#pragma unroll
        for (int mf = 0; mf < 2; ++mf) {
            int row = mf * 16 + lr;
            bf16x8 af = *reinterpret_cast<const bf16x8*>(&Al[row * 512 + ((j8 ^ (row & 7)) << 3)]);
            acc[mf] = __builtin_amdgcn_mfma_f32_16x16x32_bf16(af, bfr, acc[mf], 0, 0, 0);
        }
    }
#pragma unroll
    for (int mf = 0; mf < 2; ++mf)
#pragma unroll
        for (int r = 0; r < 4; ++r) {
            int b = mf * 16 + lg * 4 + r, o = w * 16 + lr;
            part[((long)c * B_ + b) * OUT_ + o] = acc[mf][r];
        }
}

__global__ void k_final_reduce(const float* __restrict__ part,
                               const float* __restrict__ bo, float* __restrict__ out)
{
    int i = blockIdx.x * 256 + threadIdx.x;
    int o = i & 63;
    float s = bo[o];
    for (int c = 0; c < 256; ++c) s += part[(long)c * (B_ * OUT_) + i];
    out[i] = s;
}

// ---------------- small kernels ----------------
__global__ __launch_bounds__(256) void k_maskT(const int* __restrict__ adj,
                                               u16* __restrict__ maskTb,
                                               int* __restrict__ degi)
{
    __shared__ u16 tl[64][65];
    const int j0 = blockIdx.x * 64, n0 = blockIdx.y * 64, t = threadIdx.x;
#pragma unroll
    for (int i = 0; i < 16; ++i) {
        int s = i * 256 + t, jl = s >> 6, nl = s & 63;
        tl[jl][nl] = (adj[(long)(j0 + jl) * Nn + n0 + nl] > 0) ? 0x3F80 : 0;
    }
    __syncthreads();
    if (t < 64) {
        int c = 0;
#pragma unroll
        for (int jl = 0; jl < 64; ++jl) c += (tl[jl][t] != 0);
        atomicAdd(&degi[n0 + t], c);
    }
#pragma unroll
    for (int i = 0; i < 16; ++i) {
        int s = i * 256 + t, nl = s >> 6, jl = s & 63;
        maskTb[(long)(n0 + nl) * Nn + j0 + jl] = tl[jl][nl];
    }
}

__global__ __launch_bounds__(256) void k_tpb(const float* __restrict__ in,
                                             u16* __restrict__ out, int R, int C)
{
    __shared__ float tl[64][65];
    const int c0 = blockIdx.x * 64, r0 = blockIdx.y * 64, t = threadIdx.x;
    in  += (long)blockIdx.z * R * C;
    out += (long)blockIdx.z * R * C;
#pragma unroll
    for (int i = 0; i < 16; ++i) {
        int s = i * 256 + t, rl = s >> 6, cl = s & 63;
        tl[rl][cl] = in[(long)(r0 + rl) * C + c0 + cl];
    }
    __syncthreads();
#pragma unroll
    for (int i = 0; i < 16; ++i) {
        int s = i * 256 + t, cl = s >> 6, rl = s & 63;
        out[(long)(c0 + cl) * R + r0 + rl] = f2b(tl[rl][cl]);
    }
}

__global__ void k_cvtW(const float* __restrict__ W1, const float* __restrict__ W2,
                       u16* __restrict__ W1b, u16* __restrict__ W2b)
{
    int i = blockIdx.x * 256 + threadIdx.x;
    W1b[i] = f2b(W1[i]);
    W2b[i] = f2b(W2[i]);
}

__global__ void k_cvtWo(const float* __restrict__ Wo, u16* __restrict__ Wob)
{
    long i = ((long)blockIdx.x * 256 + threadIdx.x) * 8;
    float4 a = *reinterpret_cast<const float4*>(&Wo[i]);
    float4 b = *reinterpret_cast<const float4*>(&Wo[i + 4]);
    union { u16 u[8]; float4 v; } r;
    r.u[0] = f2b(a.x); r.u[1] = f2b(a.y); r.u[2] = f2b(a.z); r.u[3] = f2b(a.w);
    r.u[4] = f2b(b.x); r.u[5] = f2b(b.y); r.u[6] = f2b(b.z); r.u[7] = f2b(b.w);
    *reinterpret_cast<float4*>(&Wob[i]) = r.v;
}

// fp32 -> bf16 row-major convert (x_in -> xA), 8 elems/thread
__global__ void k_cvtX(const float* __restrict__ x, u16* __restrict__ xo)
{
    long i = ((long)blockIdx.x * 256 + threadIdx.x) * 8;
    float4 a = *reinterpret_cast<const float4*>(&x[i]);
    float4 b = *reinterpret_cast<const float4*>(&x[i + 4]);
    union { u16 u[8]; float4 v; } r;
    r.u[0] = f2b(a.x); r.u[1] = f2b(a.y); r.u[2] = f2b(a.z); r.u[3] = f2b(a.w);
    r.u[4] = f2b(b.x); r.u[5] = f2b(b.y); r.u[6] = f2b(b.z); r.u[7] = f2b(b.w);
    *reinterpret_cast<float4*>(&xo[i]) = r.v;
}

// x[b][n][f] fp32 -> xh[b][f][n] bf16 — prolog only
__global__ __launch_bounds__(256) void k_xpose(const float* __restrict__ x,
                                               u16* __restrict__ xh)
{
    __shared__ float tile[64][132];
    const int b = blockIdx.y, n0 = blockIdx.x * 64, t = threadIdx.x;
#pragma unroll
    for (int i = 0; i < 8; ++i) {
        int s = i * 256 + t, nl = s >> 5, f4 = (s & 31) << 2;
        float4 v = *reinterpret_cast<const float4*>(&x[((long)b * Nn + n0 + nl) * F_ + f4]);
        tile[nl][f4] = v.x; tile[nl][f4 + 1] = v.y;
        tile[nl][f4 + 2] = v.z; tile[nl][f4 + 3] = v.w;
    }
    __syncthreads();
    const int f = t >> 1, nb = (t & 1) << 5;
    const long ob = ((long)b * F_ + f) * Nn + n0 + nb;
    union { u16 u[8]; float4 v; } Hv;
#pragma unroll
    for (int i = 0; i < 32; i += 8) {
#pragma unroll
        for (int j = 0; j < 8; ++j) Hv.u[j] = f2b(tile[nb + i + j][f]);
        *reinterpret_cast<float4*>(&xh[ob + i]) = Hv.v;
    }
}

// layer-0 column partials: xsp[b][seg8][f] = sum over 128 n-rows
__global__ __launch_bounds__(256) void k_xs2(const float* __restrict__ x, float* __restrict__ xsp)
{
    __shared__ float sh[2][128];
    const int seg = blockIdx.x, b = blockIdx.y, t = threadIdx.x;
    const int f = t & 127, h2 = t >> 7;
    const float* p = x + ((long)b * Nn + seg * 128 + h2 * 64) * F_ + f;
    float s = 0.f;
    for (int i = 0; i < 64; ++i) s += p[(long)i * F_];
    sh[h2][f] = s;
    __syncthreads();
    if (t < 128) xsp[((long)b * 8 + seg) * 128 + t] = sh[0][t] + sh[1][t];
}

__global__ void k_hsum(const float* __restrict__ xsp, const float* __restrict__ Wl,
                       const float* __restrict__ bsl, float* __restrict__ hsum)
{
    __shared__ float xs[128];
    const int i = blockIdx.x * 256 + threadIdx.x;
    const int b = i >> 10;
    if (threadIdx.x < 128) {
        const float* xp = xsp + (long)b * 8 * 128 + threadIdx.x;
        float v = 0.f;
#pragma unroll
        for (int sg = 0; sg < 8; ++sg) v += xp[sg * 128];
        xs[threadIdx.x] = v;
    }
    __syncthreads();
    const int e = i & 127, h = (i >> 7) & 7;
    const float* w = Wl + ((long)h * E_ + e) * F_;
    float s = 0.f;
    for (int f = 0; f < F_; ++f) s += xs[f] * w[f];
    hsum[i] = s + (float)Nn * bsl[h * E_ + e];
}

__global__ void k_d12(const float* __restrict__ As, const float* __restrict__ bs,
                      float* __restrict__ d12all)
{
    const int lyr = blockIdx.y;
    const float* Asl = As + (long)lyr * H_ * 2 * E_ * Nn;
    const float* bsl = bs + (long)lyr * H_ * E_;
    int i = blockIdx.x * 256 + threadIdx.x;
    int n = i & 1023, h = (i >> 10) & 7, w = i >> 13;
    const float* a = Asl + ((long)h * 2 * E_ + (long)w * E_) * Nn + n;
    const float* bb = bsl + h * E_;
    float s = 0.f;
    for (int e = 0; e < E_; ++e) s += bb[e] * a[(long)e * Nn];
    d12all[(long)lyr * 2 * H_ * Nn + ((long)w * H_ + h) * Nn + n] = s;
}

// fused score + attention + residual + LN1 (ILP head reduction)
__global__ __launch_bounds__(256) void k_score_ln1(
    const u16* __restrict__ xA, const u16* __restrict__ y,
    const u16* __restrict__ Ctb, const float* __restrict__ d12,
    const int* __restrict__ degi, const float* __restrict__ hsum,
    const float* __restrict__ g, const float* __restrict__ be,
    u16* __restrict__ xb)
{
    const int n = blockIdx.x, t = threadIdx.x;
    __shared__ float c1[H_][128], c2[H_][128];
    __shared__ float sbs[H_];
#pragma unroll
    for (int i = 0; i < 4; ++i) {
        int s = i * 256 + t, h = s >> 7, f = s & 127;
        c1[h][f] = b2f(Ctb[((long)(2 * h) * Nn + n) * F_ + f]);
        c2[h][f] = b2f(Ctb[((long)(2 * h + 1) * Nn + n) * F_ + f]);
    }
    if (t < H_) sbs[t] = d12[(long)t * Nn + n] + (float)degi[n] * d12[(long)(H_ + t) * Nn + n];
    __syncthreads();
    const int w = t >> 6, l = t & 63;
    const float gl0 = g[l], gl1 = g[l + 64], bl0 = be[l], bl1 = be[l + 64];
    for (int bi = 0; bi < 8; ++bi) {
        const int b = w * 8 + bi;
        const long base = ((long)b * Nn + n) * F_;
        float x0 = b2f(xA[base + l]), x1 = b2f(xA[base + l + 64]);
        float y0 = b2f(y[base + l]),  y1 = b2f(y[base + l + 64]);
        // all 8 head-partials first (independent FMAs), then batched butterfly
        float p[H_];
#pragma unroll
        for (int h = 0; h < H_; ++h)
            p[h] = x0 * c1[h][l] + x1 * c1[h][l + 64]
                 + y0 * c2[h][l] + y1 * c2[h][l + 64];
#pragma unroll
        for (int o = 32; o; o >>= 1)
#pragma unroll
            for (int h = 0; h < H_; ++h) p[h] += __shfl_xor(p[h], o);
        float a0 = 0.f, a1 = 0.f;
#pragma unroll
        for (int h = 0; h < H_; ++h) {
            float s = p[h] + sbs[h];
            float h0 = hsum[((long)b * H_ + h) * E_ + l];
            float h1 = hsum[((long)b * H_ + h) * E_ + l + 64];
            float p0 = s * h0, p1 = s * h1;
            a0 += (p0 > 0.f ? p0 : 0.01f * p0);
            a1 += (p1 > 0.f ? p1 : 0.01f * p1);
        }
        float v0 = x0 + a0, v1 = x1 + a1;
        float sum = v0 + v1;
#pragma unroll
        for (int o = 32; o; o >>= 1) sum += __shfl_xor(sum, o);
        const float mean = sum * (1.f / 128.f);
        const float d0 = v0 - mean, d1 = v1 - mean;
        float vs = d0 * d0 + d1 * d1;
#pragma unroll
        for (int o = 32; o; o >>= 1) vs += __shfl_xor(vs, o);
        const float rstd = rsqrtf(vs * (1.f / 128.f) + 1e-5f);
        xb[base + l]      = f2b(d0 * rstd * gl0 + bl0);
        xb[base + l + 64] = f2b(d1 * rstd * gl1 + bl1);
    }
}

extern "C" void kernel_launch(void* const* d_in, const int* in_sizes, int n_in,
                              void* d_out, int out_size, void* d_ws, size_t ws_size,
                              hipStream_t stream)
{
    const float* x_in = (const float*)d_in[0];
    const int*   adj  = (const int*)d_in[1];
    const float* Ws   = (const float*)d_in[2];
    const float* bs   = (const float*)d_in[3];
    const float* As   = (const float*)d_in[4];
    const float* W1   = (const float*)d_in[5];
    const float* b1   = (const float*)d_in[6];
    const float* W2   = (const float*)d_in[7];
    const float* b2   = (const float*)d_in[8];
    const float* g1   = (const float*)d_in[9];
    const float* be1  = (const float*)d_in[10];
    const float* g2   = (const float*)d_in[11];
    const float* be2  = (const float*)d_in[12];
    const float* Wo   = (const float*)d_in[13];
    const float* bo   = (const float*)d_in[14];
    float* out = (float*)d_out;

    char* wsb = (char*)d_ws;
    u16*   maskTb = (u16*)wsb;                        //   0: 2 MB
    u16*   xA     = (u16*)(wsb + (2L << 20));         //   2: 8 MB
    u16*   yb     = (u16*)(wsb + (10L << 20));        //  10: 8 MB
    u16*   CtAllb = (u16*)(wsb + (18L << 20));        //  18: 16 MB
    u16*   xB     = (u16*)(wsb + (34L << 20));        //  34: 8 MB
    u16*   xrb    = (u16*)(wsb + (42L << 20));        //  42: 8 MB
    u16*   Wob    = (u16*)(wsb + (50L << 20));        //  50: 16 MB
    float* part   = (float*)(wsb + (66L << 20));      //  66: 2 MB
    u16*   xTh    = (u16*)(wsb + (68L << 20));        //  68: 8 MB
    u16*   AsTb   = (u16*)(wsb + (76L << 20));        //  76: 16 MB
    u16*   WsTb   = (u16*)(wsb + (92L << 20));        //  92: 2 MB
    char*  S      = wsb + (94L << 20);
    int*   degi   = (int*)S;                          // 4 KB
    float* xsp    = (float*)(S + (4L << 10));         // 128 KB
    float* hsum   = (float*)(S + (132L << 10));       // 128 KB
    float* d12all = (float*)(S + (260L << 10));       // 256 KB
    u16*   W1b    = (u16*)(S + (516L << 10));         // 512 KB
    u16*   W2b    = (u16*)(S + (1028L << 10));        // 512 KB

    hipMemsetAsync(degi, 0, Nn * sizeof(int), stream);
    k_maskT<<<dim3(16, 16), 256, 0, stream>>>(adj, maskTb, degi);
    k_cvtW<<<(L_ * FF_ * F_) / 256, 256, 0, stream>>>(W1, W2, W1b, W2b);
    k_cvtWo<<<(OUT_ * KTOT) / (256 * 8), 256, 0, stream>>>(Wo, Wob);
    k_cvtX<<<(B_ * Nn * F_) / (256 * 8), 256, 0, stream>>>(x_in, xA);
    k_tpb<<<dim3(16, 4, L_ * H_), 256, 0, stream>>>(As, AsTb, 2 * E_, Nn);
    k_tpb<<<dim3(2, 2, L_ * H_), 256, 0, stream>>>(Ws, WsTb, E_, F_);
    k_xpose<<<dim3(16, B_), 256, 0, stream>>>(x_in, xTh);
    k_xs2<<<dim3(8, B_), 256, 0, stream>>>(x_in, xsp);
    k_d12<<<dim3((2 * H_ * Nn) / 256, L_), 256, 0, stream>>>(As, bs, d12all);
    k_mfma<64, 128, false, 3, 1, false, false><<<dim3(16, 1, 64), 256, 0, stream>>>(
        AsTb, 2 * E_, (long)Nn * 2 * E_, WsTb, nullptr, E_, (long)F_ * E_,
        nullptr, nullptr, CtAllb, F_, (long)Nn * F_, E_);

    for (int l = 0; l < L_; ++l) {
        const float* Wl  = Ws + (long)l * H_ * E_ * F_;
        const float* bsl = bs + (long)l * H_ * E_;

        k_mfma<128, 64, false, 3, 0, true, true><<<dim3(32, 2, 8), 256, 0, stream>>>(
            maskTb, Nn, 0L, xTh, nullptr, Nn, (long)F_ * Nn,
            nullptr, nullptr, yb, F_, (long)Nn * F_, Nn);

        k_hsum<<<(B_ * H_ * E_) / 256, 256, 0, stream>>>(xsp, Wl, bsl, hsum);
        k_score_ln1<<<Nn, 256, 0, stream>>>(
            xA, yb, CtAllb + (long)l * 16 * Nn * F_, d12all + (long)l * 2 * H_ * Nn,
            degi, hsum, g1 + l * F_, be1 + l * F_, xB);
        if (l < L_ - 1)
            k_ff_ln2<false><<<256, 512, 0, stream>>>(
                xB, W1b + (long)l * FF_ * F_, b1 + l * FF_,
                W2b + (long)l * F_ * FF_, b2 + l * F_,
                g2 + l * F_, be2 + l * F_, xA, xTh, xsp, nullptr);
        else
            k_ff_ln2<true><<<256, 512, 0, stream>>>(
                xB, W1b + (long)l * FF_ * F_, b1 + l * FF_,
                W2b + (long)l * F_ * FF_, b2 + l * F_,
                g2 + l * F_, be2 + l * F_, nullptr, nullptr, nullptr, xrb);
    }

    k_final_mfma<<<256, 256, 0, stream>>>(xrb, Wob, part);
    k_final_reduce<<<(B_ * OUT_) / 256, 256, 0, stream>>>(part, bo, out);
}